// Round 13
// baseline (535.987 us; speedup 1.0000x reference)
//
#include <hip/hip_runtime.h>
#include <cstdint>
#include <cstddef>

// ---------------- problem constants ----------------
#define TTOK 8192          // B*S tokens
#define HDIM 1024
#define IDIM 4096
#define NEXP 8
#define PMAX 18432         // 16384 + 8*256 (segment padding to 256)
#define WS_NEED 302260352ULL

// gemm1: 256(tok) x 128(wt) block, BK=32, 512 thr, ring-3 24KB slots (72KB).
// gemm2: 128x128 block, BK=32, 256 thr, ring-3 16KB slots (48KB), K-split x2.
#define SLOT1 24576
#define SLOT2 16384

typedef __attribute__((ext_vector_type(8))) short bf16x8;
typedef __attribute__((ext_vector_type(4))) float f32x4;

#define AS3 __attribute__((address_space(3)))
#define AS1 __attribute__((address_space(1)))

__device__ __forceinline__ void gld16(const void* g, void* s) {
  // async global->LDS, 16B/lane; LDS dest is wave-uniform base (+lane*16 in HW)
  __builtin_amdgcn_global_load_lds((const AS1 void*)g, (AS3 void*)s, 16, 0, 0);
}

// barrier pinned against compiler code motion (raw s_barrier is NOT an IR
// memory fence; sched_barrier(0) forbids any instruction crossing it)
__device__ __forceinline__ void pinned_barrier() {
  __builtin_amdgcn_sched_barrier(0);
  __builtin_amdgcn_s_barrier();
  __builtin_amdgcn_sched_barrier(0);
}

__device__ __forceinline__ unsigned short f2b(float f) {
  unsigned u = __builtin_bit_cast(unsigned, f);
  unsigned r = ((u >> 16) & 1u) + 0x7FFFu;   // RNE
  return (unsigned short)((u + r) >> 16);
}

__device__ __forceinline__ float b2f(unsigned short u) {
  return __builtin_bit_cast(float, ((unsigned)u) << 16);
}

// meta layout (ints): [16..23] offs, meta[24]=padded total

// ---------------- merged prep: router + packT(w1) + packT(w2) ----------------
// blocks [0,2048): router (4 tokens/block); [2048,6144): packT w1;
// [6144,10240): packT w2. All independent -> concurrent in one dispatch.
__device__ __forceinline__ void router_body(
    int bid, int t, const float* __restrict__ x, const float* __restrict__ wr,
    unsigned short* __restrict__ xb, int* __restrict__ t2e,
    float* __restrict__ t2w)
{
  const int tok = bid * 4 + (t >> 6);
  const int l = t & 63;
  const float* xr = x + (size_t)tok * HDIM;
  float acc[8] = {0.f,0.f,0.f,0.f,0.f,0.f,0.f,0.f};
  #pragma unroll
  for (int j = 0; j < 4; ++j) {
    const int base = j * 256 + l * 4;
    const float4 xv = *(const float4*)(xr + base);
    const float xa[4] = {xv.x, xv.y, xv.z, xv.w};
    ushort4 ub;
    ub.x = f2b(xa[0]); ub.y = f2b(xa[1]); ub.z = f2b(xa[2]); ub.w = f2b(xa[3]);
    *(ushort4*)(xb + (size_t)tok * HDIM + base) = ub;
    #pragma unroll
    for (int ii = 0; ii < 4; ++ii) {
      const float4 w0 = *(const float4*)(wr + (size_t)(base + ii) * 8);
      const float4 w1 = *(const float4*)(wr + (size_t)(base + ii) * 8 + 4);
      acc[0] += xa[ii] * w0.x; acc[1] += xa[ii] * w0.y;
      acc[2] += xa[ii] * w0.z; acc[3] += xa[ii] * w0.w;
      acc[4] += xa[ii] * w1.x; acc[5] += xa[ii] * w1.y;
      acc[6] += xa[ii] * w1.z; acc[7] += xa[ii] * w1.w;
    }
  }
  #pragma unroll
  for (int e = 0; e < 8; ++e) {
    float v = acc[e];
    #pragma unroll
    for (int off = 32; off > 0; off >>= 1) v += __shfl_xor(v, off);
    acc[e] = v;
  }
  if (l == 0) {
    float l0 = -1e30f; int i0 = 0;
    #pragma unroll
    for (int e = 0; e < 8; ++e) if (acc[e] > l0) { l0 = acc[e]; i0 = e; }
    float l1 = -1e30f; int i1 = (i0 == 0) ? 1 : 0;
    #pragma unroll
    for (int e = 0; e < 8; ++e) if (e != i0 && acc[e] > l1) { l1 = acc[e]; i1 = e; }
    // renormalized top2 softmax == sigmoid of gap
    const float w0 = 1.f / (1.f + expf(l1 - l0));
    t2e[tok * 2] = i0; t2e[tok * 2 + 1] = i1;
    t2w[tok * 2] = w0; t2w[tok * 2 + 1] = 1.f - w0;
  }
}

__device__ __forceinline__ void packT_body(
    int bid, int t, uint32_t* __restrict__ plds,
    const float* __restrict__ src, unsigned short* __restrict__ dst,
    int K, int N)
{
  const int tiles_n = N >> 8, tiles_k = K >> 5;
  const int e = bid / (tiles_k * tiles_n);
  const int rem = bid % (tiles_k * tiles_n);
  const int kt = rem / tiles_n, it = rem % tiles_n;
  const float* S = src + (size_t)e * K * N + (size_t)kt * 32 * N + (size_t)it * 256;
  unsigned short* D = dst + (size_t)e * N * K + (size_t)it * 256 * K + (size_t)kt * 32;
  #pragma unroll
  for (int q = 0; q < 4; ++q) {
    const int task = q * 256 + t;
    const int i4 = task & 63, kp = task >> 6;
    const float* p0 = S + (size_t)(2 * kp) * N + i4 * 4;
    const float4 r0 = *(const float4*)p0;
    const float4 r1 = *(const float4*)(p0 + N);
    const float a0[4] = {r0.x, r0.y, r0.z, r0.w};
    const float a1[4] = {r1.x, r1.y, r1.z, r1.w};
    #pragma unroll
    for (int j = 0; j < 4; ++j)
      plds[(i4 * 4 + j) * 17 + kp] = (uint32_t)f2b(a0[j]) | ((uint32_t)f2b(a1[j]) << 16);
  }
  __syncthreads();
  #pragma unroll
  for (int r = 0; r < 4; ++r) {
    const int idx = r * 256 + t;
    const int il = idx >> 2, q4 = idx & 3;
    uint4 o;
    o.x = plds[il * 17 + q4 * 4 + 0];
    o.y = plds[il * 17 + q4 * 4 + 1];
    o.z = plds[il * 17 + q4 * 4 + 2];
    o.w = plds[il * 17 + q4 * 4 + 3];
    *(uint4*)(D + (size_t)il * K + q4 * 8) = o;
  }
}

__global__ __launch_bounds__(256, 2) void prep_k(
    const float* __restrict__ x, const float* __restrict__ wr,
    unsigned short* __restrict__ xb, int* __restrict__ t2e,
    float* __restrict__ t2w,
    const float* __restrict__ w1, unsigned short* __restrict__ w1t,
    const float* __restrict__ w2, unsigned short* __restrict__ w2t)
{
  __shared__ uint32_t plds[256 * 17];
  const int bid = blockIdx.x, t = threadIdx.x;
  if (bid < 2048) {
    router_body(bid, t, x, wr, xb, t2e, t2w);
  } else if (bid < 2048 + 4096) {
    packT_body(bid - 2048, t, plds, w1, w1t, HDIM, IDIM);
  } else {
    packT_body(bid - 6144, t, plds, w2, w2t, IDIM, HDIM);
  }
}

// ---- scatter (self-counting): per-expert deterministic prefix-scan scatter --
// Each of the 8 blocks counts ALL experts (ballot histogram), derives its own
// offset, then scatters. Block e writes meta[16+e]; block 0 writes meta[24].
__global__ void scatter_k(const int* __restrict__ t2e, int* __restrict__ meta,
                          int* __restrict__ ltok, int* __restrict__ t2p)
{
  const int e = blockIdx.x;
  const int t = threadIdx.x, w = t >> 6, l = t & 63;
  __shared__ int part[4][8];
  __shared__ int soff, scnt;
  {
    int cnt[8] = {0,0,0,0,0,0,0,0};
    for (int c = 0; c < 32; ++c) {             // 4 waves x 32 x 64 = 8192
      const int tok = (w * 32 + c) * 64 + l;
      const int e0 = t2e[2 * tok], e1 = t2e[2 * tok + 1];
      #pragma unroll
      for (int i = 0; i < 8; ++i)
        cnt[i] += __popcll(__ballot(e0 == i)) + __popcll(__ballot(e1 == i));
    }
    if (l == 0) {
      #pragma unroll
      for (int i = 0; i < 8; ++i) part[w][i] = cnt[i];
    }
  }
  __syncthreads();
  if (t == 0) {
    int off = 0, mycnt = 0, tot = 0;
    #pragma unroll
    for (int i = 0; i < 8; ++i) {
      const int s = part[0][i] + part[1][i] + part[2][i] + part[3][i];
      const int pad = (s + 255) & ~255;
      if (i == e) mycnt = s;
      if (i < e) off += pad;
      tot += pad;
    }
    soff = off; scnt = mycnt;
    meta[16 + e] = off;
    if (e == 0) meta[24] = tot;
  }
  __syncthreads();
  const int off = soff, cnt = scnt;

  __shared__ int wsum[4];
  __shared__ int base;
  if (t == 0) base = 0;
  __syncthreads();
  const unsigned long long lt = (1ULL << l) - 1ULL;
  for (int c = 0; c < TTOK / 256; ++c) {
    const int tok = c * 256 + t;
    const bool m0 = (t2e[2 * tok] == e);
    const bool m1 = (t2e[2 * tok + 1] == e);
    const unsigned long long b0 = __ballot(m0);
    const unsigned long long b1 = __ballot(m1);
    const int n0 = __popcll(b0), n1 = __popcll(b1);
    const int r0 = __popcll(b0 & lt);
    const int r1 = n0 + __popcll(b1 & lt);
    if (l == 0) wsum[w] = n0 + n1;
    __syncthreads();
    int wb = base;
    #pragma unroll
    for (int i = 0; i < 4; ++i) if (i < w) wb += wsum[i];
    const int tot = wsum[0] + wsum[1] + wsum[2] + wsum[3];
    __syncthreads();
    if (t == 0) base += tot;
    if (m0) { const int p = off + wb + r0; ltok[p] = tok; t2p[2 * tok] = p; }
    if (m1) { const int p = off + wb + r1; ltok[p] = tok; t2p[2 * tok + 1] = p; }
    __syncthreads();
  }
  const int padded = (cnt + 255) & ~255;
  for (int i = cnt + t; i < padded; i += 256) ltok[off + i] = -1;
}

// LDS swizzle (bijective, verified rounds 2-12, bank-conflict==0): granule G of
// an operand region maps to (row,g): line=G>>3, q=(G&7)^(line&7),
// row=2*line+(q>>2), g=q&3. Stage keeps LDS dest linear (gld16) with
// inverse-swizzled global source; reads use line=row>>1,
// p=((row&1)*4+g)^(line&7), byte = line*128 + p*16.
// Race-safe schedule per K-tile (round-9/10 proven):
//   vmcnt(L | 0-at-tail); pinned barrier; ds_reads(slot kt); STAGE(kt+2);
//   setprio(1); MFMA; setprio(0); pinned barrier.

// ---------------- grouped GEMM1: h = silu(W1T-tile x Xg-tile + b1) -----------
// 256(tok) x 128(wt) block, 512 thr (8 waves = 2 wt-halves x 4 tok-quarters),
// wave tile 64x64. Slot: A 8KB @ +0 (128 rows), B 16KB @ +8192 (256 rows).
// 3 loads/thread/stage -> steady vmcnt(3).
__global__ __launch_bounds__(512, 4) void gemm1_k(
    const unsigned short* __restrict__ xb, const unsigned short* __restrict__ w1t,
    const float* __restrict__ b1, const int* __restrict__ meta,
    const int* __restrict__ ltok, unsigned short* __restrict__ h)
{
  const int wg = blockIdx.x;                       // 2304 = 72*32, %8==0
  const int id = (wg & 7) * (2304 / 8) + (wg >> 3);
  const int mt = id >> 5, nt = id & 31;
  if (mt * 256 >= meta[24]) return;
  int e = 0;
  #pragma unroll
  for (int i = 1; i < 8; ++i) if (meta[16 + i] <= mt * 256) e = i;

  extern __shared__ char lds[];                    // 3 slots x 24KB
  const int t = threadIdx.x;
  const int w = t >> 6, l = t & 63;
  const int wn = w & 1, wm = w >> 1;               // weight-half, token-quarter

  // A source (1 granule/thread): G = t (W1T rows = i-dim, nt tile, 128 rows)
  const unsigned short* asrc;
  {
    const int G = t;
    const int line = G >> 3, q = (G & 7) ^ (line & 7);
    const int row = 2 * line + (q >> 2), g = q & 3;
    asrc = w1t + ((size_t)e * IDIM + nt * 128 + row) * HDIM + g * 8;
  }
  // B sources (2 granules/thread): G = c*512 + t (gathered tokens, 256 rows)
  const unsigned short* bsrc[2];
  #pragma unroll
  for (int c = 0; c < 2; ++c) {
    const int G = c * 512 + t;
    const int line = G >> 3, q = (G & 7) ^ (line & 7);
    const int row = 2 * line + (q >> 2), g = q & 3;
    int tok = ltok[mt * 256 + row]; if (tok < 0) tok = 0;
    bsrc[c] = xb + (size_t)tok * HDIM + g * 8;
  }

  const int lr = l & 15, lg = l >> 4;
  f32x4 acc[4][4] = {};

  auto STAGE = [&](int kt) {
    char* sb = lds + (kt % 3) * SLOT1;
    const int ks = kt * 32;
    gld16(asrc + ks, sb + w * 1024);
    gld16(bsrc[0] + ks, sb + 8192 + w * 1024);
    gld16(bsrc[1] + ks, sb + 16384 + w * 1024);
  };

  STAGE(0); STAGE(1);
  const int NT = HDIM / 32;                        // 32
  for (int kt = 0; kt < NT; ++kt) {
    if (kt + 1 < NT) {
      asm volatile("s_waitcnt vmcnt(3)" ::: "memory");
    } else {
      asm volatile("s_waitcnt vmcnt(0)" ::: "memory");
    }
    pinned_barrier();
    const char* sl = lds + (kt % 3) * SLOT1;
    bf16x8 af[4], bf[4];
    #pragma unroll
    for (int f = 0; f < 4; ++f) {
      const int rowA = wn * 64 + f * 16 + lr;
      const int lineA = rowA >> 1;
      const int pA = (((rowA & 1) << 2) + lg) ^ (lineA & 7);
      af[f] = *(const bf16x8*)(sl + lineA * 128 + pA * 16);
      const int rowB = wm * 64 + f * 16 + lr;
      const int lineB = rowB >> 1;
      const int pB = (((rowB & 1) << 2) + lg) ^ (lineB & 7);
      bf[f] = *(const bf16x8*)(sl + 8192 + lineB * 128 + pB * 16);
    }
    if (kt + 2 < NT) STAGE(kt + 2);
    __builtin_amdgcn_s_setprio(1);
    #pragma unroll
    for (int fm = 0; fm < 4; ++fm)
      #pragma unroll
      for (int fn = 0; fn < 4; ++fn)
        acc[fm][fn] = __builtin_amdgcn_mfma_f32_16x16x32_bf16(af[fm], bf[fn], acc[fm][fn], 0, 0, 0);
    __builtin_amdgcn_s_setprio(0);
    pinned_barrier();
  }

  // epilogue: +b1, silu, packed ushort4 stores (D reg-dim = i, col-dim = token)
  const int lg4 = lg * 4;
  #pragma unroll
  for (int fm = 0; fm < 4; ++fm) {
    const int ib = nt * 128 + wn * 64 + fm * 16 + lg4;
    const float4 b1v = *(const float4*)(b1 + e * IDIM + ib);
    #pragma unroll
    for (int fn = 0; fn < 4; ++fn) {
      const int trow = mt * 256 + wm * 64 + fn * 16 + lr;
      const float v0 = acc[fm][fn][0] + b1v.x;
      const float v1 = acc[fm][fn][1] + b1v.y;
      const float v2 = acc[fm][fn][2] + b1v.z;
      const float v3 = acc[fm][fn][3] + b1v.w;
      ushort4 st;
      st.x = f2b(v0 / (1.f + __expf(-v0)));
      st.y = f2b(v1 / (1.f + __expf(-v1)));
      st.z = f2b(v2 / (1.f + __expf(-v2)));
      st.w = f2b(v3 / (1.f + __expf(-v3)));
      *(ushort4*)(h + (size_t)trow * IDIM + ib) = st;
    }
  }
}

// ---------------- grouped GEMM2: y_kh = h @ W2T^T over K-half (bf16 stores) --
// 128x128 block, 256 thr (4 waves), wave 64x64, ring-3 16KB slots.
// K-split x2: block handles kh half (2048 of K=4096) -> grid 2304 = exactly
// 3 rounds at 3 blocks/CU. Partials summed in combine_k.
__global__ __launch_bounds__(256, 3) void gemm2_k(
    const unsigned short* __restrict__ h, const unsigned short* __restrict__ w2t,
    const int* __restrict__ meta, unsigned short* __restrict__ y)
{
  const int wg = blockIdx.x;                       // 2304 = 144*8*2, %8==0
  const int id = (wg & 7) * (2304 / 8) + (wg >> 3);
  const int nt = id & 7, kh = (id >> 3) & 1, mt = id >> 4;
  if (mt * 128 >= meta[24]) return;
  int e = 0;
  #pragma unroll
  for (int i = 1; i < 8; ++i) if (meta[16 + i] <= mt * 128) e = i;

  extern __shared__ char lds[];
  const int t = threadIdx.x;
  const int w = t >> 6, l = t & 63;
  const int wn = w & 1, wm = w >> 1;
  const int kbase = kh * (IDIM / 2);               // element offset of K-half

  // A = W2T rows (hcol-dim, nt tile); B = h token rows (mt tile)
  const unsigned short* asrc[2]; const unsigned short* bsrc[2];
  #pragma unroll
  for (int c = 0; c < 2; ++c) {
    const int G = c * 256 + t;
    const int line = G >> 3, q = (G & 7) ^ (line & 7);
    const int row = 2 * line + (q >> 2), g = q & 3;
    asrc[c] = w2t + ((size_t)e * HDIM + nt * 128 + row) * IDIM + kbase + g * 8;
    bsrc[c] = h + (size_t)(mt * 128 + row) * IDIM + kbase + g * 8;
  }

  const int lr = l & 15, lg = l >> 4;
  f32x4 acc[4][4] = {};

  auto STAGE = [&](int kt) {
    char* sb = lds + (kt % 3) * SLOT2;
    const int ks = kt * 32;
    gld16(asrc[0] + ks, sb + w * 1024);
    gld16(asrc[1] + ks, sb + 4096 + w * 1024);
    gld16(bsrc[0] + ks, sb + 8192 + w * 1024);
    gld16(bsrc[1] + ks, sb + 12288 + w * 1024);
  };

  STAGE(0); STAGE(1);
  const int NT = IDIM / 2 / 32;                    // 64 (K-half)
  for (int kt = 0; kt < NT; ++kt) {
    if (kt + 1 < NT) {
      asm volatile("s_waitcnt vmcnt(4)" ::: "memory");
    } else {
      asm volatile("s_waitcnt vmcnt(0)" ::: "memory");
    }
    pinned_barrier();
    const char* sl = lds + (kt % 3) * SLOT2;
    bf16x8 af[4], bf[4];
    #pragma unroll
    for (int f = 0; f < 4; ++f) {
      const int rowA = wn * 64 + f * 16 + lr;
      const int lineA = rowA >> 1;
      const int pA = (((rowA & 1) << 2) + lg) ^ (lineA & 7);
      af[f] = *(const bf16x8*)(sl + lineA * 128 + pA * 16);
      const int rowB = wm * 64 + f * 16 + lr;
      const int lineB = rowB >> 1;
      const int pB = (((rowB & 1) << 2) + lg) ^ (lineB & 7);
      bf[f] = *(const bf16x8*)(sl + 8192 + lineB * 128 + pB * 16);
    }
    if (kt + 2 < NT) STAGE(kt + 2);
    __builtin_amdgcn_s_setprio(1);
    #pragma unroll
    for (int fm = 0; fm < 4; ++fm)
      #pragma unroll
      for (int fn = 0; fn < 4; ++fn)
        acc[fm][fn] = __builtin_amdgcn_mfma_f32_16x16x32_bf16(af[fm], bf[fn], acc[fm][fn], 0, 0, 0);
    __builtin_amdgcn_s_setprio(0);
    pinned_barrier();
  }

  // epilogue: bf16 ushort4 stores into the kh partial buffer
  unsigned short* yo = y + (size_t)kh * PMAX * HDIM;
  const int lg4 = lg * 4;
  #pragma unroll
  for (int fm = 0; fm < 4; ++fm) {
    const int colb = nt * 128 + wn * 64 + fm * 16 + lg4;
    #pragma unroll
    for (int fn = 0; fn < 4; ++fn) {
      const int row = mt * 128 + wm * 64 + fn * 16 + lr;
      ushort4 st;
      st.x = f2b(acc[fm][fn][0]); st.y = f2b(acc[fm][fn][1]);
      st.z = f2b(acc[fm][fn][2]); st.w = f2b(acc[fm][fn][3]);
      *(ushort4*)(yo + (size_t)row * HDIM + colb) = st;
    }
  }
}

// ---- combine: out[t] = w0*(y0[p0]+y1[p0]+b2[e0]) + w1*(y0[p1]+y1[p1]+b2[e1])
__global__ __launch_bounds__(256, 4) void combine_k(
    const unsigned short* __restrict__ y, const float* __restrict__ b2,
    const int* __restrict__ t2e, const float* __restrict__ t2w,
    const int* __restrict__ t2p, float* __restrict__ out)
{
  const int t = blockIdx.x * 4 + (threadIdx.x >> 6);
  const int l = threadIdx.x & 63;
  const int e0 = t2e[t * 2], e1 = t2e[t * 2 + 1];
  const float w0 = t2w[t * 2], w1v = t2w[t * 2 + 1];
  const int p0 = t2p[t * 2], p1 = t2p[t * 2 + 1];
  const unsigned short* ya0 = y + (size_t)p0 * HDIM;
  const unsigned short* yb0 = y + (size_t)PMAX * HDIM + (size_t)p0 * HDIM;
  const unsigned short* ya1 = y + (size_t)p1 * HDIM;
  const unsigned short* yb1 = y + (size_t)PMAX * HDIM + (size_t)p1 * HDIM;
  const float* bb0 = b2 + e0 * HDIM;
  const float* bb1 = b2 + e1 * HDIM;
  float* o = out + (size_t)t * HDIM;
  #pragma unroll
  for (int j = 0; j < 4; ++j) {
    const int c = j * 256 + l * 4;
    const ushort4 a0 = *(const ushort4*)(ya0 + c);
    const ushort4 a1 = *(const ushort4*)(yb0 + c);
    const ushort4 b0v = *(const ushort4*)(ya1 + c);
    const ushort4 b1u = *(const ushort4*)(yb1 + c);
    const float4 c0 = *(const float4*)(bb0 + c);
    const float4 c1 = *(const float4*)(bb1 + c);
    float4 r;
    r.x = w0 * (b2f(a0.x) + b2f(a1.x) + c0.x) + w1v * (b2f(b0v.x) + b2f(b1u.x) + c1.x);
    r.y = w0 * (b2f(a0.y) + b2f(a1.y) + c0.y) + w1v * (b2f(b0v.y) + b2f(b1u.y) + c1.y);
    r.z = w0 * (b2f(a0.z) + b2f(a1.z) + c0.z) + w1v * (b2f(b0v.z) + b2f(b1u.z) + c1.z);
    r.w = w0 * (b2f(a0.w) + b2f(a1.w) + c0.w) + w1v * (b2f(b0v.w) + b2f(b1u.w) + c1.w);
    *(float4*)(o + c) = r;
  }
}

__global__ void sentinel_k(float* out) { out[0] = 1.0e6f; }

// ---------------- launcher ----------------
extern "C" void kernel_launch(void* const* d_in, const int* in_sizes, int n_in,
                              void* d_out, int out_size, void* d_ws, size_t ws_size,
                              hipStream_t stream)
{
  (void)in_sizes; (void)n_in; (void)out_size;
  const float* x  = (const float*)d_in[0];
  const float* wr = (const float*)d_in[1];
  const float* w1 = (const float*)d_in[2];
  const float* b1 = (const float*)d_in[3];
  const float* w2 = (const float*)d_in[4];
  const float* b2 = (const float*)d_in[5];
  float* out = (float*)d_out;
  char* ws = (char*)d_ws;

  if (ws_size < WS_NEED) { sentinel_k<<<1, 1, 0, stream>>>(out); return; }

  unsigned short* xb  = (unsigned short*)(ws);                 // 16.78 MB
  unsigned short* w1t = (unsigned short*)(ws + 16777216);      // 67.1 MB
  unsigned short* w2t = (unsigned short*)(ws + 83886080);      // 67.1 MB
  unsigned short* h   = (unsigned short*)(ws + 150994944);     // 151.0 MB
  int*   t2e  = (int*)(ws + 301989888);
  float* t2w  = (float*)(ws + 302055424);
  int*   ltok = (int*)(ws + 302120960);
  int*   t2p  = (int*)(ws + 302194688);
  int*   meta = (int*)(ws + 302260224);
  // y partials (bf16, 2 x 37.7MB) alias xb+w1t (dead after gemm1):
  // [0, 75.5MB) < w2t start 83.9MB, and w2t/h stay live for gemm2.
  unsigned short* y = (unsigned short*)(ws);

  // allow dynamic LDS on the GEMMs (non-stream op; graph-capture safe)
  hipFuncSetAttribute((const void*)gemm1_k, hipFuncAttributeMaxDynamicSharedMemorySize, 3 * SLOT1);
  hipFuncSetAttribute((const void*)gemm2_k, hipFuncAttributeMaxDynamicSharedMemorySize, 3 * SLOT2);

  // merged router + packT(w1) + packT(w2): 2048 + 4096 + 4096 blocks
  prep_k<<<10240, 256, 0, stream>>>(x, wr, xb, t2e, t2w, w1, w1t, w2, w2t);
  scatter_k<<<NEXP, 256, 0, stream>>>(t2e, meta, ltok, t2p);

  gemm1_k<<<72 * 32, 512, 3 * SLOT1, stream>>>(xb, w1t, b1, meta, ltok, h);
  gemm2_k<<<144 * 8 * 2, 256, 3 * SLOT2, stream>>>(h, w2t, meta, y);
  combine_k<<<TTOK / 4, 256, 0, stream>>>(y, b2, t2e, t2w, t2p, out);
}

// Round 14
// 520.519 us; speedup vs baseline: 1.0297x; 1.0297x over previous
//
#include <hip/hip_runtime.h>
#include <cstdint>
#include <cstddef>

// ---------------- problem constants ----------------
#define TTOK 8192          // B*S tokens
#define HDIM 1024
#define IDIM 4096
#define NEXP 8
#define PMAX 18432         // 16384 + 8*256 (segment padding to 256)
#define WS_NEED 302260352ULL

// gemm1: 256(wt) x 256(tok) block, BK=64, 512 thr (8 waves, wave 128x64),
//        2x64KB LDS double-buffer, m201-style 8-phase counted-vmcnt schedule.
// gemm2: 128x128 block, BK=32, 256 thr, ring-3 16KB slots (48KB), K-split x2.
#define SLOT2 16384

typedef __attribute__((ext_vector_type(8))) short bf16x8;
typedef __attribute__((ext_vector_type(4))) float f32x4;

#define AS3 __attribute__((address_space(3)))
#define AS1 __attribute__((address_space(1)))

__device__ __forceinline__ void gld16(const void* g, void* s) {
  // async global->LDS, 16B/lane; LDS dest is wave-uniform base (+lane*16 in HW)
  __builtin_amdgcn_global_load_lds((const AS1 void*)g, (AS3 void*)s, 16, 0, 0);
}

// barrier pinned against compiler code motion (raw s_barrier is NOT an IR
// memory fence; sched_barrier(0) forbids any instruction crossing it)
__device__ __forceinline__ void pinned_barrier() {
  __builtin_amdgcn_sched_barrier(0);
  __builtin_amdgcn_s_barrier();
  __builtin_amdgcn_sched_barrier(0);
}

__device__ __forceinline__ void wait_lds() {
  asm volatile("s_waitcnt lgkmcnt(0)" ::: "memory");
  __builtin_amdgcn_sched_barrier(0);   // rule 18: MFMA must not hoist above
}

__device__ __forceinline__ unsigned short f2b(float f) {
  unsigned u = __builtin_bit_cast(unsigned, f);
  unsigned r = ((u >> 16) & 1u) + 0x7FFFu;   // RNE
  return (unsigned short)((u + r) >> 16);
}

__device__ __forceinline__ float b2f(unsigned short u) {
  return __builtin_bit_cast(float, ((unsigned)u) << 16);
}

// meta layout (ints): [16..23] offs, meta[24]=padded total

// ---------------- merged prep: router + packT(w1) + packT(w2) ----------------
__device__ __forceinline__ void router_body(
    int bid, int t, const float* __restrict__ x, const float* __restrict__ wr,
    unsigned short* __restrict__ xb, int* __restrict__ t2e,
    float* __restrict__ t2w)
{
  const int tok = bid * 4 + (t >> 6);
  const int l = t & 63;
  const float* xr = x + (size_t)tok * HDIM;
  float acc[8] = {0.f,0.f,0.f,0.f,0.f,0.f,0.f,0.f};
  #pragma unroll
  for (int j = 0; j < 4; ++j) {
    const int base = j * 256 + l * 4;
    const float4 xv = *(const float4*)(xr + base);
    const float xa[4] = {xv.x, xv.y, xv.z, xv.w};
    ushort4 ub;
    ub.x = f2b(xa[0]); ub.y = f2b(xa[1]); ub.z = f2b(xa[2]); ub.w = f2b(xa[3]);
    *(ushort4*)(xb + (size_t)tok * HDIM + base) = ub;
    #pragma unroll
    for (int ii = 0; ii < 4; ++ii) {
      const float4 w0 = *(const float4*)(wr + (size_t)(base + ii) * 8);
      const float4 w1 = *(const float4*)(wr + (size_t)(base + ii) * 8 + 4);
      acc[0] += xa[ii] * w0.x; acc[1] += xa[ii] * w0.y;
      acc[2] += xa[ii] * w0.z; acc[3] += xa[ii] * w0.w;
      acc[4] += xa[ii] * w1.x; acc[5] += xa[ii] * w1.y;
      acc[6] += xa[ii] * w1.z; acc[7] += xa[ii] * w1.w;
    }
  }
  #pragma unroll
  for (int e = 0; e < 8; ++e) {
    float v = acc[e];
    #pragma unroll
    for (int off = 32; off > 0; off >>= 1) v += __shfl_xor(v, off);
    acc[e] = v;
  }
  if (l == 0) {
    float l0 = -1e30f; int i0 = 0;
    #pragma unroll
    for (int e = 0; e < 8; ++e) if (acc[e] > l0) { l0 = acc[e]; i0 = e; }
    float l1 = -1e30f; int i1 = (i0 == 0) ? 1 : 0;
    #pragma unroll
    for (int e = 0; e < 8; ++e) if (e != i0 && acc[e] > l1) { l1 = acc[e]; i1 = e; }
    const float w0 = 1.f / (1.f + expf(l1 - l0));
    t2e[tok * 2] = i0; t2e[tok * 2 + 1] = i1;
    t2w[tok * 2] = w0; t2w[tok * 2 + 1] = 1.f - w0;
  }
}

__device__ __forceinline__ void packT_body(
    int bid, int t, uint32_t* __restrict__ plds,
    const float* __restrict__ src, unsigned short* __restrict__ dst,
    int K, int N)
{
  const int tiles_n = N >> 8, tiles_k = K >> 5;
  const int e = bid / (tiles_k * tiles_n);
  const int rem = bid % (tiles_k * tiles_n);
  const int kt = rem / tiles_n, it = rem % tiles_n;
  const float* S = src + (size_t)e * K * N + (size_t)kt * 32 * N + (size_t)it * 256;
  unsigned short* D = dst + (size_t)e * N * K + (size_t)it * 256 * K + (size_t)kt * 32;
  #pragma unroll
  for (int q = 0; q < 4; ++q) {
    const int task = q * 256 + t;
    const int i4 = task & 63, kp = task >> 6;
    const float* p0 = S + (size_t)(2 * kp) * N + i4 * 4;
    const float4 r0 = *(const float4*)p0;
    const float4 r1 = *(const float4*)(p0 + N);
    const float a0[4] = {r0.x, r0.y, r0.z, r0.w};
    const float a1[4] = {r1.x, r1.y, r1.z, r1.w};
    #pragma unroll
    for (int j = 0; j < 4; ++j)
      plds[(i4 * 4 + j) * 17 + kp] = (uint32_t)f2b(a0[j]) | ((uint32_t)f2b(a1[j]) << 16);
  }
  __syncthreads();
  #pragma unroll
  for (int r = 0; r < 4; ++r) {
    const int idx = r * 256 + t;
    const int il = idx >> 2, q4 = idx & 3;
    uint4 o;
    o.x = plds[il * 17 + q4 * 4 + 0];
    o.y = plds[il * 17 + q4 * 4 + 1];
    o.z = plds[il * 17 + q4 * 4 + 2];
    o.w = plds[il * 17 + q4 * 4 + 3];
    *(uint4*)(D + (size_t)il * K + q4 * 8) = o;
  }
}

__global__ __launch_bounds__(256, 2) void prep_k(
    const float* __restrict__ x, const float* __restrict__ wr,
    unsigned short* __restrict__ xb, int* __restrict__ t2e,
    float* __restrict__ t2w,
    const float* __restrict__ w1, unsigned short* __restrict__ w1t,
    const float* __restrict__ w2, unsigned short* __restrict__ w2t)
{
  __shared__ uint32_t plds[256 * 17];
  const int bid = blockIdx.x, t = threadIdx.x;
  if (bid < 2048) {
    router_body(bid, t, x, wr, xb, t2e, t2w);
  } else if (bid < 2048 + 4096) {
    packT_body(bid - 2048, t, plds, w1, w1t, HDIM, IDIM);
  } else {
    packT_body(bid - 6144, t, plds, w2, w2t, IDIM, HDIM);
  }
}

// ---- scatter (self-counting): per-expert deterministic prefix-scan scatter --
__global__ void scatter_k(const int* __restrict__ t2e, int* __restrict__ meta,
                          int* __restrict__ ltok, int* __restrict__ t2p)
{
  const int e = blockIdx.x;
  const int t = threadIdx.x, w = t >> 6, l = t & 63;
  __shared__ int part[4][8];
  __shared__ int soff, scnt;
  {
    int cnt[8] = {0,0,0,0,0,0,0,0};
    for (int c = 0; c < 32; ++c) {
      const int tok = (w * 32 + c) * 64 + l;
      const int e0 = t2e[2 * tok], e1 = t2e[2 * tok + 1];
      #pragma unroll
      for (int i = 0; i < 8; ++i)
        cnt[i] += __popcll(__ballot(e0 == i)) + __popcll(__ballot(e1 == i));
    }
    if (l == 0) {
      #pragma unroll
      for (int i = 0; i < 8; ++i) part[w][i] = cnt[i];
    }
  }
  __syncthreads();
  if (t == 0) {
    int off = 0, mycnt = 0, tot = 0;
    #pragma unroll
    for (int i = 0; i < 8; ++i) {
      const int s = part[0][i] + part[1][i] + part[2][i] + part[3][i];
      const int pad = (s + 255) & ~255;
      if (i == e) mycnt = s;
      if (i < e) off += pad;
      tot += pad;
    }
    soff = off; scnt = mycnt;
    meta[16 + e] = off;
    if (e == 0) meta[24] = tot;
  }
  __syncthreads();
  const int off = soff, cnt = scnt;

  __shared__ int wsum[4];
  __shared__ int base;
  if (t == 0) base = 0;
  __syncthreads();
  const unsigned long long lt = (1ULL << l) - 1ULL;
  for (int c = 0; c < TTOK / 256; ++c) {
    const int tok = c * 256 + t;
    const bool m0 = (t2e[2 * tok] == e);
    const bool m1 = (t2e[2 * tok + 1] == e);
    const unsigned long long b0 = __ballot(m0);
    const unsigned long long b1 = __ballot(m1);
    const int n0 = __popcll(b0), n1 = __popcll(b1);
    const int r0 = __popcll(b0 & lt);
    const int r1 = n0 + __popcll(b1 & lt);
    if (l == 0) wsum[w] = n0 + n1;
    __syncthreads();
    int wb = base;
    #pragma unroll
    for (int i = 0; i < 4; ++i) if (i < w) wb += wsum[i];
    const int tot = wsum[0] + wsum[1] + wsum[2] + wsum[3];
    __syncthreads();
    if (t == 0) base += tot;
    if (m0) { const int p = off + wb + r0; ltok[p] = tok; t2p[2 * tok] = p; }
    if (m1) { const int p = off + wb + r1; ltok[p] = tok; t2p[2 * tok + 1] = p; }
    __syncthreads();
  }
  const int padded = (cnt + 255) & ~255;
  for (int i = cnt + t; i < padded; i += 256) ltok[off + i] = -1;
}

// ================== gemm1: m201-style 8-phase, 256x256, BK=64 ==============
// 8 waves = wm(2 A-halves) x wn(4 B-quarters); wave tile 128(A) x 64(B).
// LDS buf (64KB): [A0 16K][A1 16K][B0 16K][B1 16K], x2 buffers.
// Half-tile = 128 rows x 64 K (128B rows). Swizzle: granule G of a half:
// row=G>>3, g=(G&7)^(row&7) -> linear gld16 dest + inverse-swizzled source;
// read byte = row*128 + ((ks*4+lg)^(row&7))*16  (uniform bank spread).
// Phases (per iter = tiles t0=2i buf0, t1=2i+1 buf1; stage set t2,t3 = +2):
//  P1: rd A(fm0-3)x2k+B(fn01)x2k buf0 | stg A0t1 | bar | lgkm0 | 16 MFMA | bar
//  P2: rd B(fn23) buf0              | stg A1t1 | ...  (acc[fm0-3][fn23])
//  P3: rd A(fm4-7) buf0             | stg B0t2 [pf]
//  P4: (no reads, reuse regs)       | stg B1t2 [pf] | vmcnt(pf?4:0) | bar...
//  P5: rd A(fm0-3)+B(fn01) buf1     | stg A0t2 [pf]
//  P6: rd B(fn23) buf1              | stg A1t2 [pf]
//  P7: rd A(fm4-7) buf1             | stg B0t3 [pf]
//  P8: (no reads)                   | stg B1t3 [pf] | [pf] vmcnt(4) | bar...
// vmcnt ledger (2 loads/half): P4-end guards buf1 reads (need A1t1@P2; after:
// B0t2,B1t2 = 4). P8-end guards next buf0 (need A1t0@P6; after: B0t1,B1t1=4).
// Free-before-stage: every staged half was last read >=1 closing barrier ago.
__global__ __launch_bounds__(512, 2) void gemm1_k(
    const unsigned short* __restrict__ xb, const unsigned short* __restrict__ w1t,
    const float* __restrict__ b1, const int* __restrict__ meta,
    const int* __restrict__ ltok, unsigned short* __restrict__ h)
{
  const int wg = blockIdx.x;                       // 1152 = 72*16, %8==0
  const int id = (wg & 7) * (1152 / 8) + (wg >> 3);
  const int mt = id >> 4, nt = id & 15;
  if (mt * 256 >= meta[24]) return;
  int e = 0;
  #pragma unroll
  for (int i = 1; i < 8; ++i) if (meta[16 + i] <= mt * 256) e = i;

  extern __shared__ char lds[];                    // 2 x 64KB
  const int t = threadIdx.x;
  const int w = t >> 6, l = t & 63;
  const int wm = w >> 2, wn = w & 3;               // A-half, B-quarter
  const int lr = l & 15, lg = l >> 4;

  // staging sources: per half, thread covers granules G=t (row=t>>3) and
  // G=t+512 (row+64); g identical for both (64%8==0).
  const int srow = t >> 3;
  const int sg = (t & 7) ^ (srow & 7);
  const unsigned short* asrc[2][2];
  const unsigned short* bsrc[2][2];
  #pragma unroll
  for (int hh = 0; hh < 2; ++hh)
    #pragma unroll
    for (int s = 0; s < 2; ++s) {
      const int row = hh * 128 + s * 64 + srow;
      asrc[hh][s] = w1t + ((size_t)e * IDIM + nt * 256 + row) * HDIM + sg * 8;
      int tok = ltok[mt * 256 + row]; if (tok < 0) tok = 0;
      bsrc[hh][s] = xb + (size_t)tok * HDIM + sg * 8;
    }

  auto STG = [&](int kt, int o, int hh) {          // o: 0=A,1=B
    char* d = lds + (kt & 1) * 65536 + o * 32768 + hh * 16384 + w * 1024;
    const int ks = kt * 64;
    const unsigned short* s0 = o ? bsrc[hh][0] : asrc[hh][0];
    const unsigned short* s1 = o ? bsrc[hh][1] : asrc[hh][1];
    gld16(s0 + ks, d);
    gld16(s1 + ks, d + 8192);
  };

  f32x4 acc[8][4] = {};
  const int NITER = (HDIM / 64) / 2;               // 8

  // prologue: B0.0,B1.0,A0.0,A1.0,B0.1,B1.1 (12 loads); guard buf0 reads
  STG(0, 1, 0); STG(0, 1, 1);
  STG(0, 0, 0); STG(0, 0, 1);
  STG(1, 1, 0); STG(1, 1, 1);
  asm volatile("s_waitcnt vmcnt(4)" ::: "memory");
  pinned_barrier();

  for (int it = 0; it < NITER; ++it) {
    const int t1 = 2 * it + 1, t2 = 2 * it + 2, t3 = 2 * it + 3;
    const bool pf = (it + 1 < NITER);
    const char* sA0 = lds + wm * 16384;                    // buf0 A region
    const char* sB0 = lds + 32768 + (wn >> 1) * 16384;     // buf0 B region
    const char* sA1 = sA0 + 65536;
    const char* sB1 = sB0 + 65536;
    const int rB = (wn & 1) * 64;                          // B row base in half

    bf16x8 af[4][2], b01[2][2], b23[2][2];

    // -------- P1 --------
    #pragma unroll
    for (int fm = 0; fm < 4; ++fm)
      #pragma unroll
      for (int ks = 0; ks < 2; ++ks) {
        const int row = fm * 16 + lr;
        af[fm][ks] = *(const bf16x8*)(sA0 + row * 128 + (((ks << 2) + lg) ^ (row & 7)) * 16);
      }
    #pragma unroll
    for (int fn = 0; fn < 2; ++fn)
      #pragma unroll
      for (int ks = 0; ks < 2; ++ks) {
        const int row = rB + fn * 16 + lr;
        b01[fn][ks] = *(const bf16x8*)(sB0 + row * 128 + (((ks << 2) + lg) ^ (row & 7)) * 16);
      }
    STG(t1, 0, 0);
    pinned_barrier(); wait_lds();
    __builtin_amdgcn_s_setprio(1);
    #pragma unroll
    for (int fm = 0; fm < 4; ++fm)
      #pragma unroll
      for (int fn = 0; fn < 2; ++fn) {
        acc[fm][fn] = __builtin_amdgcn_mfma_f32_16x16x32_bf16(af[fm][0], b01[fn][0], acc[fm][fn], 0, 0, 0);
        acc[fm][fn] = __builtin_amdgcn_mfma_f32_16x16x32_bf16(af[fm][1], b01[fn][1], acc[fm][fn], 0, 0, 0);
      }
    __builtin_amdgcn_s_setprio(0);
    pinned_barrier();

    // -------- P2 --------
    #pragma unroll
    for (int fn = 0; fn < 2; ++fn)
      #pragma unroll
      for (int ks = 0; ks < 2; ++ks) {
        const int row = rB + (fn + 2) * 16 + lr;
        b23[fn][ks] = *(const bf16x8*)(sB0 + row * 128 + (((ks << 2) + lg) ^ (row & 7)) * 16);
      }
    STG(t1, 0, 1);
    pinned_barrier(); wait_lds();
    __builtin_amdgcn_s_setprio(1);
    #pragma unroll
    for (int fm = 0; fm < 4; ++fm)
      #pragma unroll
      for (int fn = 0; fn < 2; ++fn) {
        acc[fm][fn + 2] = __builtin_amdgcn_mfma_f32_16x16x32_bf16(af[fm][0], b23[fn][0], acc[fm][fn + 2], 0, 0, 0);
        acc[fm][fn + 2] = __builtin_amdgcn_mfma_f32_16x16x32_bf16(af[fm][1], b23[fn][1], acc[fm][fn + 2], 0, 0, 0);
      }
    __builtin_amdgcn_s_setprio(0);
    pinned_barrier();

    // -------- P3 --------
    #pragma unroll
    for (int fm = 0; fm < 4; ++fm)
      #pragma unroll
      for (int ks = 0; ks < 2; ++ks) {
        const int row = (fm + 4) * 16 + lr;
        af[fm][ks] = *(const bf16x8*)(sA0 + row * 128 + (((ks << 2) + lg) ^ (row & 7)) * 16);
      }
    if (pf) STG(t2, 1, 0);
    pinned_barrier(); wait_lds();
    __builtin_amdgcn_s_setprio(1);
    #pragma unroll
    for (int fm = 0; fm < 4; ++fm)
      #pragma unroll
      for (int fn = 0; fn < 2; ++fn) {
        acc[fm + 4][fn] = __builtin_amdgcn_mfma_f32_16x16x32_bf16(af[fm][0], b01[fn][0], acc[fm + 4][fn], 0, 0, 0);
        acc[fm + 4][fn] = __builtin_amdgcn_mfma_f32_16x16x32_bf16(af[fm][1], b01[fn][1], acc[fm + 4][fn], 0, 0, 0);
      }
    __builtin_amdgcn_s_setprio(0);
    pinned_barrier();

    // -------- P4 --------
    if (pf) STG(t2, 1, 1);
    if (pf) { asm volatile("s_waitcnt vmcnt(4)" ::: "memory"); }
    else    { asm volatile("s_waitcnt vmcnt(0)" ::: "memory"); }
    pinned_barrier();
    __builtin_amdgcn_s_setprio(1);
    #pragma unroll
    for (int fm = 0; fm < 4; ++fm)
      #pragma unroll
      for (int fn = 0; fn < 2; ++fn) {
        acc[fm + 4][fn + 2] = __builtin_amdgcn_mfma_f32_16x16x32_bf16(af[fm][0], b23[fn][0], acc[fm + 4][fn + 2], 0, 0, 0);
        acc[fm + 4][fn + 2] = __builtin_amdgcn_mfma_f32_16x16x32_bf16(af[fm][1], b23[fn][1], acc[fm + 4][fn + 2], 0, 0, 0);
      }
    __builtin_amdgcn_s_setprio(0);
    pinned_barrier();

    // -------- P5 --------
    #pragma unroll
    for (int fm = 0; fm < 4; ++fm)
      #pragma unroll
      for (int ks = 0; ks < 2; ++ks) {
        const int row = fm * 16 + lr;
        af[fm][ks] = *(const bf16x8*)(sA1 + row * 128 + (((ks << 2) + lg) ^ (row & 7)) * 16);
      }
    #pragma unroll
    for (int fn = 0; fn < 2; ++fn)
      #pragma unroll
      for (int ks = 0; ks < 2; ++ks) {
        const int row = rB + fn * 16 + lr;
        b01[fn][ks] = *(const bf16x8*)(sB1 + row * 128 + (((ks << 2) + lg) ^ (row & 7)) * 16);
      }
    if (pf) STG(t2, 0, 0);
    pinned_barrier(); wait_lds();
    __builtin_amdgcn_s_setprio(1);
    #pragma unroll
    for (int fm = 0; fm < 4; ++fm)
      #pragma unroll
      for (int fn = 0; fn < 2; ++fn) {
        acc[fm][fn] = __builtin_amdgcn_mfma_f32_16x16x32_bf16(af[fm][0], b01[fn][0], acc[fm][fn], 0, 0, 0);
        acc[fm][fn] = __builtin_amdgcn_mfma_f32_16x16x32_bf16(af[fm][1], b01[fn][1], acc[fm][fn], 0, 0, 0);
      }
    __builtin_amdgcn_s_setprio(0);
    pinned_barrier();

    // -------- P6 --------
    #pragma unroll
    for (int fn = 0; fn < 2; ++fn)
      #pragma unroll
      for (int ks = 0; ks < 2; ++ks) {
        const int row = rB + (fn + 2) * 16 + lr;
        b23[fn][ks] = *(const bf16x8*)(sB1 + row * 128 + (((ks << 2) + lg) ^ (row & 7)) * 16);
      }
    if (pf) STG(t2, 0, 1);
    pinned_barrier(); wait_lds();
    __builtin_amdgcn_s_setprio(1);
    #pragma unroll
    for (int fm = 0; fm < 4; ++fm)
      #pragma unroll
      for (int fn = 0; fn < 2; ++fn) {
        acc[fm][fn + 2] = __builtin_amdgcn_mfma_f32_16x16x32_bf16(af[fm][0], b23[fn][0], acc[fm][fn + 2], 0, 0, 0);
        acc[fm][fn + 2] = __builtin_amdgcn_mfma_f32_16x16x32_bf16(af[fm][1], b23[fn][1], acc[fm][fn + 2], 0, 0, 0);
      }
    __builtin_amdgcn_s_setprio(0);
    pinned_barrier();

    // -------- P7 --------
    #pragma unroll
    for (int fm = 0; fm < 4; ++fm)
      #pragma unroll
      for (int ks = 0; ks < 2; ++ks) {
        const int row = (fm + 4) * 16 + lr;
        af[fm][ks] = *(const bf16x8*)(sA1 + row * 128 + (((ks << 2) + lg) ^ (row & 7)) * 16);
      }
    if (pf) STG(t3, 1, 0);
    pinned_barrier(); wait_lds();
    __builtin_amdgcn_s_setprio(1);
    #pragma unroll
    for (int fm = 0; fm < 4; ++fm)
      #pragma unroll
      for (int fn = 0; fn < 2; ++fn) {
        acc[fm + 4][fn] = __builtin_amdgcn_mfma_f32_16x16x32_bf16(af[fm][0], b01[fn][0], acc[fm + 4][fn], 0, 0, 0);
        acc[fm + 4][fn] = __builtin_amdgcn_mfma_f32_16x16x32_bf16(af[fm][1], b01[fn][1], acc[fm + 4][fn], 0, 0, 0);
      }
    __builtin_amdgcn_s_setprio(0);
    pinned_barrier();

    // -------- P8 --------
    if (pf) {
      STG(t3, 1, 1);
      asm volatile("s_waitcnt vmcnt(4)" ::: "memory");
    }
    pinned_barrier();
    __builtin_amdgcn_s_setprio(1);
    #pragma unroll
    for (int fm = 0; fm < 4; ++fm)
      #pragma unroll
      for (int fn = 0; fn < 2; ++fn) {
        acc[fm + 4][fn + 2] = __builtin_amdgcn_mfma_f32_16x16x32_bf16(af[fm][0], b23[fn][0], acc[fm + 4][fn + 2], 0, 0, 0);
        acc[fm + 4][fn + 2] = __builtin_amdgcn_mfma_f32_16x16x32_bf16(af[fm][1], b23[fn][1], acc[fm + 4][fn + 2], 0, 0, 0);
      }
    __builtin_amdgcn_s_setprio(0);
    pinned_barrier();
  }

  // epilogue: +b1, silu, packed ushort4 stores (D reg-dim = i, col = token)
  const int lg4 = lg * 4;
  #pragma unroll
  for (int fm = 0; fm < 8; ++fm) {
    const int ib = nt * 256 + wm * 128 + fm * 16 + lg4;
    const float4 b1v = *(const float4*)(b1 + e * IDIM + ib);
    #pragma unroll
    for (int fn = 0; fn < 4; ++fn) {
      const int trow = mt * 256 + wn * 64 + fn * 16 + lr;
      const float v0 = acc[fm][fn][0] + b1v.x;
      const float v1 = acc[fm][fn][1] + b1v.y;
      const float v2 = acc[fm][fn][2] + b1v.z;
      const float v3 = acc[fm][fn][3] + b1v.w;
      ushort4 st;
      st.x = f2b(v0 / (1.f + __expf(-v0)));
      st.y = f2b(v1 / (1.f + __expf(-v1)));
      st.z = f2b(v2 / (1.f + __expf(-v2)));
      st.w = f2b(v3 / (1.f + __expf(-v3)));
      *(ushort4*)(h + (size_t)trow * IDIM + ib) = st;
    }
  }
}

// ---------------- grouped GEMM2: y_kh = h @ W2T^T over K-half (R13) ---------
__global__ __launch_bounds__(256, 3) void gemm2_k(
    const unsigned short* __restrict__ h, const unsigned short* __restrict__ w2t,
    const int* __restrict__ meta, unsigned short* __restrict__ y)
{
  const int wg = blockIdx.x;                       // 2304
  const int id = (wg & 7) * (2304 / 8) + (wg >> 3);
  const int nt = id & 7, kh = (id >> 3) & 1, mt = id >> 4;
  if (mt * 128 >= meta[24]) return;
  int e = 0;
  #pragma unroll
  for (int i = 1; i < 8; ++i) if (meta[16 + i] <= mt * 128) e = i;

  extern __shared__ char lds[];
  const int t = threadIdx.x;
  const int w = t >> 6, l = t & 63;
  const int wn = w & 1, wm = w >> 1;
  const int kbase = kh * (IDIM / 2);

  const unsigned short* asrc[2]; const unsigned short* bsrc[2];
  #pragma unroll
  for (int c = 0; c < 2; ++c) {
    const int G = c * 256 + t;
    const int line = G >> 3, q = (G & 7) ^ (line & 7);
    const int row = 2 * line + (q >> 2), g = q & 3;
    asrc[c] = w2t + ((size_t)e * HDIM + nt * 128 + row) * IDIM + kbase + g * 8;
    bsrc[c] = h + (size_t)(mt * 128 + row) * IDIM + kbase + g * 8;
  }

  const int lr = l & 15, lg = l >> 4;
  f32x4 acc[4][4] = {};

  auto STAGE = [&](int kt) {
    char* sb = lds + (kt % 3) * SLOT2;
    const int ks = kt * 32;
    gld16(asrc[0] + ks, sb + w * 1024);
    gld16(asrc[1] + ks, sb + 4096 + w * 1024);
    gld16(bsrc[0] + ks, sb + 8192 + w * 1024);
    gld16(bsrc[1] + ks, sb + 12288 + w * 1024);
  };

  STAGE(0); STAGE(1);
  const int NT = IDIM / 2 / 32;                    // 64
  for (int kt = 0; kt < NT; ++kt) {
    if (kt + 1 < NT) {
      asm volatile("s_waitcnt vmcnt(4)" ::: "memory");
    } else {
      asm volatile("s_waitcnt vmcnt(0)" ::: "memory");
    }
    pinned_barrier();
    const char* sl = lds + (kt % 3) * SLOT2;
    bf16x8 af[4], bf[4];
    #pragma unroll
    for (int f = 0; f < 4; ++f) {
      const int rowA = wn * 64 + f * 16 + lr;
      const int lineA = rowA >> 1;
      const int pA = (((rowA & 1) << 2) + lg) ^ (lineA & 7);
      af[f] = *(const bf16x8*)(sl + lineA * 128 + pA * 16);
      const int rowB = wm * 64 + f * 16 + lr;
      const int lineB = rowB >> 1;
      const int pB = (((rowB & 1) << 2) + lg) ^ (lineB & 7);
      bf[f] = *(const bf16x8*)(sl + 8192 + lineB * 128 + pB * 16);
    }
    if (kt + 2 < NT) STAGE(kt + 2);
    __builtin_amdgcn_s_setprio(1);
    #pragma unroll
    for (int fm = 0; fm < 4; ++fm)
      #pragma unroll
      for (int fn = 0; fn < 4; ++fn)
        acc[fm][fn] = __builtin_amdgcn_mfma_f32_16x16x32_bf16(af[fm], bf[fn], acc[fm][fn], 0, 0, 0);
    __builtin_amdgcn_s_setprio(0);
    pinned_barrier();
  }

  unsigned short* yo = y + (size_t)kh * PMAX * HDIM;
  const int lg4 = lg * 4;
  #pragma unroll
  for (int fm = 0; fm < 4; ++fm) {
    const int colb = nt * 128 + wn * 64 + fm * 16 + lg4;
    #pragma unroll
    for (int fn = 0; fn < 4; ++fn) {
      const int row = mt * 128 + wm * 64 + fn * 16 + lr;
      ushort4 st;
      st.x = f2b(acc[fm][fn][0]); st.y = f2b(acc[fm][fn][1]);
      st.z = f2b(acc[fm][fn][2]); st.w = f2b(acc[fm][fn][3]);
      *(ushort4*)(yo + (size_t)row * HDIM + colb) = st;
    }
  }
}

// ---- combine: out[t] = w0*(y0[p0]+y1[p0]+b2[e0]) + w1*(y0[p1]+y1[p1]+b2[e1])
__global__ __launch_bounds__(256, 4) void combine_k(
    const unsigned short* __restrict__ y, const float* __restrict__ b2,
    const int* __restrict__ t2e, const float* __restrict__ t2w,
    const int* __restrict__ t2p, float* __restrict__ out)
{
  const int t = blockIdx.x * 4 + (threadIdx.x >> 6);
  const int l = threadIdx.x & 63;
  const int e0 = t2e[t * 2], e1 = t2e[t * 2 + 1];
  const float w0 = t2w[t * 2], w1v = t2w[t * 2 + 1];
  const int p0 = t2p[t * 2], p1 = t2p[t * 2 + 1];
  const unsigned short* ya0 = y + (size_t)p0 * HDIM;
  const unsigned short* yb0 = y + (size_t)PMAX * HDIM + (size_t)p0 * HDIM;
  const unsigned short* ya1 = y + (size_t)p1 * HDIM;
  const unsigned short* yb1 = y + (size_t)PMAX * HDIM + (size_t)p1 * HDIM;
  const float* bb0 = b2 + e0 * HDIM;
  const float* bb1 = b2 + e1 * HDIM;
  float* o = out + (size_t)t * HDIM;
  #pragma unroll
  for (int j = 0; j < 4; ++j) {
    const int c = j * 256 + l * 4;
    const ushort4 a0 = *(const ushort4*)(ya0 + c);
    const ushort4 a1 = *(const ushort4*)(yb0 + c);
    const ushort4 b0v = *(const ushort4*)(ya1 + c);
    const ushort4 b1u = *(const ushort4*)(yb1 + c);
    const float4 c0 = *(const float4*)(bb0 + c);
    const float4 c1 = *(const float4*)(bb1 + c);
    float4 r;
    r.x = w0 * (b2f(a0.x) + b2f(a1.x) + c0.x) + w1v * (b2f(b0v.x) + b2f(b1u.x) + c1.x);
    r.y = w0 * (b2f(a0.y) + b2f(a1.y) + c0.y) + w1v * (b2f(b0v.y) + b2f(b1u.y) + c1.y);
    r.z = w0 * (b2f(a0.z) + b2f(a1.z) + c0.z) + w1v * (b2f(b0v.z) + b2f(b1u.z) + c1.z);
    r.w = w0 * (b2f(a0.w) + b2f(a1.w) + c0.w) + w1v * (b2f(b0v.w) + b2f(b1u.w) + c1.w);
    *(float4*)(o + c) = r;
  }
}

__global__ void sentinel_k(float* out) { out[0] = 1.0e6f; }

// ---------------- launcher ----------------
extern "C" void kernel_launch(void* const* d_in, const int* in_sizes, int n_in,
                              void* d_out, int out_size, void* d_ws, size_t ws_size,
                              hipStream_t stream)
{
  (void)in_sizes; (void)n_in; (void)out_size;
  const float* x  = (const float*)d_in[0];
  const float* wr = (const float*)d_in[1];
  const float* w1 = (const float*)d_in[2];
  const float* b1 = (const float*)d_in[3];
  const float* w2 = (const float*)d_in[4];
  const float* b2 = (const float*)d_in[5];
  float* out = (float*)d_out;
  char* ws = (char*)d_ws;

  if (ws_size < WS_NEED) { sentinel_k<<<1, 1, 0, stream>>>(out); return; }

  unsigned short* xb  = (unsigned short*)(ws);                 // 16.78 MB
  unsigned short* w1t = (unsigned short*)(ws + 16777216);      // 67.1 MB
  unsigned short* w2t = (unsigned short*)(ws + 83886080);      // 67.1 MB
  unsigned short* h   = (unsigned short*)(ws + 150994944);     // 151.0 MB
  int*   t2e  = (int*)(ws + 301989888);
  float* t2w  = (float*)(ws + 302055424);
  int*   ltok = (int*)(ws + 302120960);
  int*   t2p  = (int*)(ws + 302194688);
  int*   meta = (int*)(ws + 302260224);
  // y partials (bf16, 2 x 37.7MB) alias xb+w1t (dead after gemm1)
  unsigned short* y = (unsigned short*)(ws);

  hipFuncSetAttribute((const void*)gemm1_k, hipFuncAttributeMaxDynamicSharedMemorySize, 131072);
  hipFuncSetAttribute((const void*)gemm2_k, hipFuncAttributeMaxDynamicSharedMemorySize, 3 * SLOT2);

  prep_k<<<10240, 256, 0, stream>>>(x, wr, xb, t2e, t2w, w1, w1t, w2, w2t);
  scatter_k<<<NEXP, 256, 0, stream>>>(t2e, meta, ltok, t2p);

  gemm1_k<<<72 * 16, 512, 131072, stream>>>(xb, w1t, b1, meta, ltok, h);
  gemm2_k<<<144 * 8 * 2, 256, 3 * SLOT2, stream>>>(h, w2t, meta, y);
  combine_k<<<TTOK / 4, 256, 0, stream>>>(y, b2, t2e, t2w, t2p, out);
}

// Round 15
// 518.888 us; speedup vs baseline: 1.0330x; 1.0031x over previous
//
#include <hip/hip_runtime.h>
#include <cstdint>
#include <cstddef>

// ---------------- problem constants ----------------
#define TTOK 8192          // B*S tokens
#define HDIM 1024
#define IDIM 4096
#define NEXP 8
#define PMAX 18432         // 16384 + 8*256 (segment padding to 256)
#define WS_NEED 302260352ULL

// gemm1: 256(wt) x 256(tok) block, BK=64, 512 thr (8 waves, wave 128x64),
//        2x64KB LDS double-buffer, 8-phase counted-vmcnt schedule.
// gemm2: 128x128 block, BK=32, 256 thr, ring-3 16KB slots (48KB), K-split x2.
#define SLOT2 16384

typedef __attribute__((ext_vector_type(8))) short bf16x8;
typedef __attribute__((ext_vector_type(4))) float f32x4;

#define AS3 __attribute__((address_space(3)))
#define AS1 __attribute__((address_space(1)))

__device__ __forceinline__ void gld16(const void* g, void* s) {
  // async global->LDS, 16B/lane; LDS dest is wave-uniform base (+lane*16 in HW)
  __builtin_amdgcn_global_load_lds((const AS1 void*)g, (AS3 void*)s, 16, 0, 0);
}

// Phase-opening barrier with SELECTIVE fence (round-15): mask 0xF lets
// ALU/VALU/SALU/MFMA float across (overlap), but VMEM (gld16) and DS
// (ds_read) may NOT cross -> preserves the R8-race guard (a ds_read rising
// above the barrier could read a slot another wave hasn't staged yet) and
// own-wave LDS write-after-read order, without m141-style full order-pinning.
__device__ __forceinline__ void bar_fence() {
  __builtin_amdgcn_s_barrier();
  __builtin_amdgcn_sched_barrier(0xF);
}
// Phase-closing barrier: raw. Everything sinking below is safe (slots are
// not restaged for >=2 barriers; register deps order MFMA vs its reads).
__device__ __forceinline__ void bar_raw() {
  __builtin_amdgcn_s_barrier();
}

__device__ __forceinline__ void wait_lds() {
  asm volatile("s_waitcnt lgkmcnt(0)" ::: "memory");
  __builtin_amdgcn_sched_barrier(0);   // rule 18: MFMA must not hoist above
}

__device__ __forceinline__ unsigned short f2b(float f) {
  unsigned u = __builtin_bit_cast(unsigned, f);
  unsigned r = ((u >> 16) & 1u) + 0x7FFFu;   // RNE
  return (unsigned short)((u + r) >> 16);
}

__device__ __forceinline__ float b2f(unsigned short u) {
  return __builtin_bit_cast(float, ((unsigned)u) << 16);
}

// meta layout (ints): [16..23] offs, meta[24]=padded total

// ---------------- merged prep: router + packT(w1) + packT(w2) ----------------
__device__ __forceinline__ void router_body(
    int bid, int t, const float* __restrict__ x, const float* __restrict__ wr,
    unsigned short* __restrict__ xb, int* __restrict__ t2e,
    float* __restrict__ t2w)
{
  const int tok = bid * 4 + (t >> 6);
  const int l = t & 63;
  const float* xr = x + (size_t)tok * HDIM;
  float acc[8] = {0.f,0.f,0.f,0.f,0.f,0.f,0.f,0.f};
  #pragma unroll
  for (int j = 0; j < 4; ++j) {
    const int base = j * 256 + l * 4;
    const float4 xv = *(const float4*)(xr + base);
    const float xa[4] = {xv.x, xv.y, xv.z, xv.w};
    ushort4 ub;
    ub.x = f2b(xa[0]); ub.y = f2b(xa[1]); ub.z = f2b(xa[2]); ub.w = f2b(xa[3]);
    *(ushort4*)(xb + (size_t)tok * HDIM + base) = ub;
    #pragma unroll
    for (int ii = 0; ii < 4; ++ii) {
      const float4 w0 = *(const float4*)(wr + (size_t)(base + ii) * 8);
      const float4 w1 = *(const float4*)(wr + (size_t)(base + ii) * 8 + 4);
      acc[0] += xa[ii] * w0.x; acc[1] += xa[ii] * w0.y;
      acc[2] += xa[ii] * w0.z; acc[3] += xa[ii] * w0.w;
      acc[4] += xa[ii] * w1.x; acc[5] += xa[ii] * w1.y;
      acc[6] += xa[ii] * w1.z; acc[7] += xa[ii] * w1.w;
    }
  }
  #pragma unroll
  for (int e = 0; e < 8; ++e) {
    float v = acc[e];
    #pragma unroll
    for (int off = 32; off > 0; off >>= 1) v += __shfl_xor(v, off);
    acc[e] = v;
  }
  if (l == 0) {
    float l0 = -1e30f; int i0 = 0;
    #pragma unroll
    for (int e = 0; e < 8; ++e) if (acc[e] > l0) { l0 = acc[e]; i0 = e; }
    float l1 = -1e30f; int i1 = (i0 == 0) ? 1 : 0;
    #pragma unroll
    for (int e = 0; e < 8; ++e) if (e != i0 && acc[e] > l1) { l1 = acc[e]; i1 = e; }
    const float w0 = 1.f / (1.f + expf(l1 - l0));
    t2e[tok * 2] = i0; t2e[tok * 2 + 1] = i1;
    t2w[tok * 2] = w0; t2w[tok * 2 + 1] = 1.f - w0;
  }
}

__device__ __forceinline__ void packT_body(
    int bid, int t, uint32_t* __restrict__ plds,
    const float* __restrict__ src, unsigned short* __restrict__ dst,
    int K, int N)
{
  const int tiles_n = N >> 8, tiles_k = K >> 5;
  const int e = bid / (tiles_k * tiles_n);
  const int rem = bid % (tiles_k * tiles_n);
  const int kt = rem / tiles_n, it = rem % tiles_n;
  const float* S = src + (size_t)e * K * N + (size_t)kt * 32 * N + (size_t)it * 256;
  unsigned short* D = dst + (size_t)e * N * K + (size_t)it * 256 * K + (size_t)kt * 32;
  #pragma unroll
  for (int q = 0; q < 4; ++q) {
    const int task = q * 256 + t;
    const int i4 = task & 63, kp = task >> 6;
    const float* p0 = S + (size_t)(2 * kp) * N + i4 * 4;
    const float4 r0 = *(const float4*)p0;
    const float4 r1 = *(const float4*)(p0 + N);
    const float a0[4] = {r0.x, r0.y, r0.z, r0.w};
    const float a1[4] = {r1.x, r1.y, r1.z, r1.w};
    #pragma unroll
    for (int j = 0; j < 4; ++j)
      plds[(i4 * 4 + j) * 17 + kp] = (uint32_t)f2b(a0[j]) | ((uint32_t)f2b(a1[j]) << 16);
  }
  __syncthreads();
  #pragma unroll
  for (int r = 0; r < 4; ++r) {
    const int idx = r * 256 + t;
    const int il = idx >> 2, q4 = idx & 3;
    uint4 o;
    o.x = plds[il * 17 + q4 * 4 + 0];
    o.y = plds[il * 17 + q4 * 4 + 1];
    o.z = plds[il * 17 + q4 * 4 + 2];
    o.w = plds[il * 17 + q4 * 4 + 3];
    *(uint4*)(D + (size_t)il * K + q4 * 8) = o;
  }
}

__global__ __launch_bounds__(256, 2) void prep_k(
    const float* __restrict__ x, const float* __restrict__ wr,
    unsigned short* __restrict__ xb, int* __restrict__ t2e,
    float* __restrict__ t2w,
    const float* __restrict__ w1, unsigned short* __restrict__ w1t,
    const float* __restrict__ w2, unsigned short* __restrict__ w2t)
{
  __shared__ uint32_t plds[256 * 17];
  const int bid = blockIdx.x, t = threadIdx.x;
  if (bid < 2048) {
    router_body(bid, t, x, wr, xb, t2e, t2w);
  } else if (bid < 2048 + 4096) {
    packT_body(bid - 2048, t, plds, w1, w1t, HDIM, IDIM);
  } else {
    packT_body(bid - 6144, t, plds, w2, w2t, IDIM, HDIM);
  }
}

// ---- scatter (self-counting): per-expert deterministic prefix-scan scatter --
__global__ void scatter_k(const int* __restrict__ t2e, int* __restrict__ meta,
                          int* __restrict__ ltok, int* __restrict__ t2p)
{
  const int e = blockIdx.x;
  const int t = threadIdx.x, w = t >> 6, l = t & 63;
  __shared__ int part[4][8];
  __shared__ int soff, scnt;
  {
    int cnt[8] = {0,0,0,0,0,0,0,0};
    for (int c = 0; c < 32; ++c) {
      const int tok = (w * 32 + c) * 64 + l;
      const int e0 = t2e[2 * tok], e1 = t2e[2 * tok + 1];
      #pragma unroll
      for (int i = 0; i < 8; ++i)
        cnt[i] += __popcll(__ballot(e0 == i)) + __popcll(__ballot(e1 == i));
    }
    if (l == 0) {
      #pragma unroll
      for (int i = 0; i < 8; ++i) part[w][i] = cnt[i];
    }
  }
  __syncthreads();
  if (t == 0) {
    int off = 0, mycnt = 0, tot = 0;
    #pragma unroll
    for (int i = 0; i < 8; ++i) {
      const int s = part[0][i] + part[1][i] + part[2][i] + part[3][i];
      const int pad = (s + 255) & ~255;
      if (i == e) mycnt = s;
      if (i < e) off += pad;
      tot += pad;
    }
    soff = off; scnt = mycnt;
    meta[16 + e] = off;
    if (e == 0) meta[24] = tot;
  }
  __syncthreads();
  const int off = soff, cnt = scnt;

  __shared__ int wsum[4];
  __shared__ int base;
  if (t == 0) base = 0;
  __syncthreads();
  const unsigned long long lt = (1ULL << l) - 1ULL;
  for (int c = 0; c < TTOK / 256; ++c) {
    const int tok = c * 256 + t;
    const bool m0 = (t2e[2 * tok] == e);
    const bool m1 = (t2e[2 * tok + 1] == e);
    const unsigned long long b0 = __ballot(m0);
    const unsigned long long b1 = __ballot(m1);
    const int n0 = __popcll(b0), n1 = __popcll(b1);
    const int r0 = __popcll(b0 & lt);
    const int r1 = n0 + __popcll(b1 & lt);
    if (l == 0) wsum[w] = n0 + n1;
    __syncthreads();
    int wb = base;
    #pragma unroll
    for (int i = 0; i < 4; ++i) if (i < w) wb += wsum[i];
    const int tot = wsum[0] + wsum[1] + wsum[2] + wsum[3];
    __syncthreads();
    if (t == 0) base += tot;
    if (m0) { const int p = off + wb + r0; ltok[p] = tok; t2p[2 * tok] = p; }
    if (m1) { const int p = off + wb + r1; ltok[p] = tok; t2p[2 * tok + 1] = p; }
    __syncthreads();
  }
  const int padded = (cnt + 255) & ~255;
  for (int i = cnt + t; i < padded; i += 256) ltok[off + i] = -1;
}

// ================== gemm1: 8-phase, 256x256, BK=64 (see R14 ledger) ========
__global__ __launch_bounds__(512, 2) void gemm1_k(
    const unsigned short* __restrict__ xb, const unsigned short* __restrict__ w1t,
    const float* __restrict__ b1, const int* __restrict__ meta,
    const int* __restrict__ ltok, unsigned short* __restrict__ h)
{
  const int wg = blockIdx.x;                       // 1152 = 72*16, %8==0
  const int id = (wg & 7) * (1152 / 8) + (wg >> 3);
  const int mt = id >> 4, nt = id & 15;
  if (mt * 256 >= meta[24]) return;
  int e = 0;
  #pragma unroll
  for (int i = 1; i < 8; ++i) if (meta[16 + i] <= mt * 256) e = i;

  extern __shared__ char lds[];                    // 2 x 64KB
  const int t = threadIdx.x;
  const int w = t >> 6, l = t & 63;
  const int wm = w >> 2, wn = w & 3;               // A-half, B-quarter
  const int lr = l & 15, lg = l >> 4;

  const int srow = t >> 3;
  const int sg = (t & 7) ^ (srow & 7);
  const unsigned short* asrc[2][2];
  const unsigned short* bsrc[2][2];
  #pragma unroll
  for (int hh = 0; hh < 2; ++hh)
    #pragma unroll
    for (int s = 0; s < 2; ++s) {
      const int row = hh * 128 + s * 64 + srow;
      asrc[hh][s] = w1t + ((size_t)e * IDIM + nt * 256 + row) * HDIM + sg * 8;
      int tok = ltok[mt * 256 + row]; if (tok < 0) tok = 0;
      bsrc[hh][s] = xb + (size_t)tok * HDIM + sg * 8;
    }

  auto STG = [&](int kt, int o, int hh) {          // o: 0=A,1=B
    char* d = lds + (kt & 1) * 65536 + o * 32768 + hh * 16384 + w * 1024;
    const int ks = kt * 64;
    const unsigned short* s0 = o ? bsrc[hh][0] : asrc[hh][0];
    const unsigned short* s1 = o ? bsrc[hh][1] : asrc[hh][1];
    gld16(s0 + ks, d);
    gld16(s1 + ks, d + 8192);
  };

  f32x4 acc[8][4] = {};
  const int NITER = (HDIM / 64) / 2;               // 8

  STG(0, 1, 0); STG(0, 1, 1);
  STG(0, 0, 0); STG(0, 0, 1);
  STG(1, 1, 0); STG(1, 1, 1);
  asm volatile("s_waitcnt vmcnt(4)" ::: "memory");
  bar_fence();

  for (int it = 0; it < NITER; ++it) {
    const int t1 = 2 * it + 1, t2 = 2 * it + 2, t3 = 2 * it + 3;
    const bool pf = (it + 1 < NITER);
    const char* sA0 = lds + wm * 16384;
    const char* sB0 = lds + 32768 + (wn >> 1) * 16384;
    const char* sA1 = sA0 + 65536;
    const char* sB1 = sB0 + 65536;
    const int rB = (wn & 1) * 64;

    bf16x8 af[4][2], b01[2][2], b23[2][2];

    // -------- P1 --------
    #pragma unroll
    for (int fm = 0; fm < 4; ++fm)
      #pragma unroll
      for (int ks = 0; ks < 2; ++ks) {
        const int row = fm * 16 + lr;
        af[fm][ks] = *(const bf16x8*)(sA0 + row * 128 + (((ks << 2) + lg) ^ (row & 7)) * 16);
      }
    #pragma unroll
    for (int fn = 0; fn < 2; ++fn)
      #pragma unroll
      for (int ks = 0; ks < 2; ++ks) {
        const int row = rB + fn * 16 + lr;
        b01[fn][ks] = *(const bf16x8*)(sB0 + row * 128 + (((ks << 2) + lg) ^ (row & 7)) * 16);
      }
    STG(t1, 0, 0);
    bar_fence(); wait_lds();
    __builtin_amdgcn_s_setprio(1);
    #pragma unroll
    for (int fm = 0; fm < 4; ++fm)
      #pragma unroll
      for (int fn = 0; fn < 2; ++fn) {
        acc[fm][fn] = __builtin_amdgcn_mfma_f32_16x16x32_bf16(af[fm][0], b01[fn][0], acc[fm][fn], 0, 0, 0);
        acc[fm][fn] = __builtin_amdgcn_mfma_f32_16x16x32_bf16(af[fm][1], b01[fn][1], acc[fm][fn], 0, 0, 0);
      }
    __builtin_amdgcn_s_setprio(0);
    bar_raw();

    // -------- P2 --------
    #pragma unroll
    for (int fn = 0; fn < 2; ++fn)
      #pragma unroll
      for (int ks = 0; ks < 2; ++ks) {
        const int row = rB + (fn + 2) * 16 + lr;
        b23[fn][ks] = *(const bf16x8*)(sB0 + row * 128 + (((ks << 2) + lg) ^ (row & 7)) * 16);
      }
    STG(t1, 0, 1);
    bar_fence(); wait_lds();
    __builtin_amdgcn_s_setprio(1);
    #pragma unroll
    for (int fm = 0; fm < 4; ++fm)
      #pragma unroll
      for (int fn = 0; fn < 2; ++fn) {
        acc[fm][fn + 2] = __builtin_amdgcn_mfma_f32_16x16x32_bf16(af[fm][0], b23[fn][0], acc[fm][fn + 2], 0, 0, 0);
        acc[fm][fn + 2] = __builtin_amdgcn_mfma_f32_16x16x32_bf16(af[fm][1], b23[fn][1], acc[fm][fn + 2], 0, 0, 0);
      }
    __builtin_amdgcn_s_setprio(0);
    bar_raw();

    // -------- P3 --------
    #pragma unroll
    for (int fm = 0; fm < 4; ++fm)
      #pragma unroll
      for (int ks = 0; ks < 2; ++ks) {
        const int row = (fm + 4) * 16 + lr;
        af[fm][ks] = *(const bf16x8*)(sA0 + row * 128 + (((ks << 2) + lg) ^ (row & 7)) * 16);
      }
    if (pf) STG(t2, 1, 0);
    bar_fence(); wait_lds();
    __builtin_amdgcn_s_setprio(1);
    #pragma unroll
    for (int fm = 0; fm < 4; ++fm)
      #pragma unroll
      for (int fn = 0; fn < 2; ++fn) {
        acc[fm + 4][fn] = __builtin_amdgcn_mfma_f32_16x16x32_bf16(af[fm][0], b01[fn][0], acc[fm + 4][fn], 0, 0, 0);
        acc[fm + 4][fn] = __builtin_amdgcn_mfma_f32_16x16x32_bf16(af[fm][1], b01[fn][1], acc[fm + 4][fn], 0, 0, 0);
      }
    __builtin_amdgcn_s_setprio(0);
    bar_raw();

    // -------- P4 --------
    if (pf) STG(t2, 1, 1);
    if (pf) { asm volatile("s_waitcnt vmcnt(4)" ::: "memory"); }
    else    { asm volatile("s_waitcnt vmcnt(0)" ::: "memory"); }
    bar_fence();
    __builtin_amdgcn_s_setprio(1);
    #pragma unroll
    for (int fm = 0; fm < 4; ++fm)
      #pragma unroll
      for (int fn = 0; fn < 2; ++fn) {
        acc[fm + 4][fn + 2] = __builtin_amdgcn_mfma_f32_16x16x32_bf16(af[fm][0], b23[fn][0], acc[fm + 4][fn + 2], 0, 0, 0);
        acc[fm + 4][fn + 2] = __builtin_amdgcn_mfma_f32_16x16x32_bf16(af[fm][1], b23[fn][1], acc[fm + 4][fn + 2], 0, 0, 0);
      }
    __builtin_amdgcn_s_setprio(0);
    bar_raw();

    // -------- P5 --------
    #pragma unroll
    for (int fm = 0; fm < 4; ++fm)
      #pragma unroll
      for (int ks = 0; ks < 2; ++ks) {
        const int row = fm * 16 + lr;
        af[fm][ks] = *(const bf16x8*)(sA1 + row * 128 + (((ks << 2) + lg) ^ (row & 7)) * 16);
      }
    #pragma unroll
    for (int fn = 0; fn < 2; ++fn)
      #pragma unroll
      for (int ks = 0; ks < 2; ++ks) {
        const int row = rB + fn * 16 + lr;
        b01[fn][ks] = *(const bf16x8*)(sB1 + row * 128 + (((ks << 2) + lg) ^ (row & 7)) * 16);
      }
    if (pf) STG(t2, 0, 0);
    bar_fence(); wait_lds();
    __builtin_amdgcn_s_setprio(1);
    #pragma unroll
    for (int fm = 0; fm < 4; ++fm)
      #pragma unroll
      for (int fn = 0; fn < 2; ++fn) {
        acc[fm][fn] = __builtin_amdgcn_mfma_f32_16x16x32_bf16(af[fm][0], b01[fn][0], acc[fm][fn], 0, 0, 0);
        acc[fm][fn] = __builtin_amdgcn_mfma_f32_16x16x32_bf16(af[fm][1], b01[fn][1], acc[fm][fn], 0, 0, 0);
      }
    __builtin_amdgcn_s_setprio(0);
    bar_raw();

    // -------- P6 --------
    #pragma unroll
    for (int fn = 0; fn < 2; ++fn)
      #pragma unroll
      for (int ks = 0; ks < 2; ++ks) {
        const int row = rB + (fn + 2) * 16 + lr;
        b23[fn][ks] = *(const bf16x8*)(sB1 + row * 128 + (((ks << 2) + lg) ^ (row & 7)) * 16);
      }
    if (pf) STG(t2, 0, 1);
    bar_fence(); wait_lds();
    __builtin_amdgcn_s_setprio(1);
    #pragma unroll
    for (int fm = 0; fm < 4; ++fm)
      #pragma unroll
      for (int fn = 0; fn < 2; ++fn) {
        acc[fm][fn + 2] = __builtin_amdgcn_mfma_f32_16x16x32_bf16(af[fm][0], b23[fn][0], acc[fm][fn + 2], 0, 0, 0);
        acc[fm][fn + 2] = __builtin_amdgcn_mfma_f32_16x16x32_bf16(af[fm][1], b23[fn][1], acc[fm][fn + 2], 0, 0, 0);
      }
    __builtin_amdgcn_s_setprio(0);
    bar_raw();

    // -------- P7 --------
    #pragma unroll
    for (int fm = 0; fm < 4; ++fm)
      #pragma unroll
      for (int ks = 0; ks < 2; ++ks) {
        const int row = (fm + 4) * 16 + lr;
        af[fm][ks] = *(const bf16x8*)(sA1 + row * 128 + (((ks << 2) + lg) ^ (row & 7)) * 16);
      }
    if (pf) STG(t3, 1, 0);
    bar_fence(); wait_lds();
    __builtin_amdgcn_s_setprio(1);
    #pragma unroll
    for (int fm = 0; fm < 4; ++fm)
      #pragma unroll
      for (int fn = 0; fn < 2; ++fn) {
        acc[fm + 4][fn] = __builtin_amdgcn_mfma_f32_16x16x32_bf16(af[fm][0], b01[fn][0], acc[fm + 4][fn], 0, 0, 0);
        acc[fm + 4][fn] = __builtin_amdgcn_mfma_f32_16x16x32_bf16(af[fm][1], b01[fn][1], acc[fm + 4][fn], 0, 0, 0);
      }
    __builtin_amdgcn_s_setprio(0);
    bar_raw();

    // -------- P8 --------
    if (pf) {
      STG(t3, 1, 1);
      asm volatile("s_waitcnt vmcnt(4)" ::: "memory");
    }
    bar_fence();
    __builtin_amdgcn_s_setprio(1);
    #pragma unroll
    for (int fm = 0; fm < 4; ++fm)
      #pragma unroll
      for (int fn = 0; fn < 2; ++fn) {
        acc[fm + 4][fn + 2] = __builtin_amdgcn_mfma_f32_16x16x32_bf16(af[fm][0], b23[fn][0], acc[fm + 4][fn + 2], 0, 0, 0);
        acc[fm + 4][fn + 2] = __builtin_amdgcn_mfma_f32_16x16x32_bf16(af[fm][1], b23[fn][1], acc[fm + 4][fn + 2], 0, 0, 0);
      }
    __builtin_amdgcn_s_setprio(0);
    bar_raw();
  }

  // epilogue: +b1, silu, packed ushort4 stores (D reg-dim = i, col = token)
  const int lg4 = lg * 4;
  #pragma unroll
  for (int fm = 0; fm < 8; ++fm) {
    const int ib = nt * 256 + wm * 128 + fm * 16 + lg4;
    const float4 b1v = *(const float4*)(b1 + e * IDIM + ib);
    #pragma unroll
    for (int fn = 0; fn < 4; ++fn) {
      const int trow = mt * 256 + wn * 64 + fn * 16 + lr;
      const float v0 = acc[fm][fn][0] + b1v.x;
      const float v1 = acc[fm][fn][1] + b1v.y;
      const float v2 = acc[fm][fn][2] + b1v.z;
      const float v3 = acc[fm][fn][3] + b1v.w;
      ushort4 st;
      st.x = f2b(v0 / (1.f + __expf(-v0)));
      st.y = f2b(v1 / (1.f + __expf(-v1)));
      st.z = f2b(v2 / (1.f + __expf(-v2)));
      st.w = f2b(v3 / (1.f + __expf(-v3)));
      *(ushort4*)(h + (size_t)trow * IDIM + ib) = st;
    }
  }
}

// ---------------- grouped GEMM2: y_kh = h @ W2T^T over K-half ---------------
__global__ __launch_bounds__(256, 3) void gemm2_k(
    const unsigned short* __restrict__ h, const unsigned short* __restrict__ w2t,
    const int* __restrict__ meta, unsigned short* __restrict__ y)
{
  const int wg = blockIdx.x;                       // 2304
  const int id = (wg & 7) * (2304 / 8) + (wg >> 3);
  const int nt = id & 7, kh = (id >> 3) & 1, mt = id >> 4;
  if (mt * 128 >= meta[24]) return;
  int e = 0;
  #pragma unroll
  for (int i = 1; i < 8; ++i) if (meta[16 + i] <= mt * 128) e = i;

  extern __shared__ char lds[];
  const int t = threadIdx.x;
  const int w = t >> 6, l = t & 63;
  const int wn = w & 1, wm = w >> 1;
  const int kbase = kh * (IDIM / 2);

  const unsigned short* asrc[2]; const unsigned short* bsrc[2];
  #pragma unroll
  for (int c = 0; c < 2; ++c) {
    const int G = c * 256 + t;
    const int line = G >> 3, q = (G & 7) ^ (line & 7);
    const int row = 2 * line + (q >> 2), g = q & 3;
    asrc[c] = w2t + ((size_t)e * HDIM + nt * 128 + row) * IDIM + kbase + g * 8;
    bsrc[c] = h + (size_t)(mt * 128 + row) * IDIM + kbase + g * 8;
  }

  const int lr = l & 15, lg = l >> 4;
  f32x4 acc[4][4] = {};

  auto STAGE = [&](int kt) {
    char* sb = lds + (kt % 3) * SLOT2;
    const int ks = kt * 32;
    gld16(asrc[0] + ks, sb + w * 1024);
    gld16(asrc[1] + ks, sb + 4096 + w * 1024);
    gld16(bsrc[0] + ks, sb + 8192 + w * 1024);
    gld16(bsrc[1] + ks, sb + 12288 + w * 1024);
  };

  STAGE(0); STAGE(1);
  const int NT = IDIM / 2 / 32;                    // 64
  for (int kt = 0; kt < NT; ++kt) {
    if (kt + 1 < NT) {
      asm volatile("s_waitcnt vmcnt(4)" ::: "memory");
    } else {
      asm volatile("s_waitcnt vmcnt(0)" ::: "memory");
    }
    bar_fence();
    const char* sl = lds + (kt % 3) * SLOT2;
    bf16x8 af[4], bf[4];
    #pragma unroll
    for (int f = 0; f < 4; ++f) {
      const int rowA = wn * 64 + f * 16 + lr;
      const int lineA = rowA >> 1;
      const int pA = (((rowA & 1) << 2) + lg) ^ (lineA & 7);
      af[f] = *(const bf16x8*)(sl + lineA * 128 + pA * 16);
      const int rowB = wm * 64 + f * 16 + lr;
      const int lineB = rowB >> 1;
      const int pB = (((rowB & 1) << 2) + lg) ^ (lineB & 7);
      bf[f] = *(const bf16x8*)(sl + 8192 + lineB * 128 + pB * 16);
    }
    if (kt + 2 < NT) STAGE(kt + 2);
    __builtin_amdgcn_s_setprio(1);
    #pragma unroll
    for (int fm = 0; fm < 4; ++fm)
      #pragma unroll
      for (int fn = 0; fn < 4; ++fn)
        acc[fm][fn] = __builtin_amdgcn_mfma_f32_16x16x32_bf16(af[fm], bf[fn], acc[fm][fn], 0, 0, 0);
    __builtin_amdgcn_s_setprio(0);
    bar_raw();
  }

  unsigned short* yo = y + (size_t)kh * PMAX * HDIM;
  const int lg4 = lg * 4;
  #pragma unroll
  for (int fm = 0; fm < 4; ++fm) {
    const int colb = nt * 128 + wn * 64 + fm * 16 + lg4;
    #pragma unroll
    for (int fn = 0; fn < 4; ++fn) {
      const int row = mt * 128 + wm * 64 + fn * 16 + lr;
      ushort4 st;
      st.x = f2b(acc[fm][fn][0]); st.y = f2b(acc[fm][fn][1]);
      st.z = f2b(acc[fm][fn][2]); st.w = f2b(acc[fm][fn][3]);
      *(ushort4*)(yo + (size_t)row * HDIM + colb) = st;
    }
  }
}

// ---- combine: out[t] = w0*(y0[p0]+y1[p0]+b2[e0]) + w1*(y0[p1]+y1[p1]+b2[e1])
__global__ __launch_bounds__(256, 4) void combine_k(
    const unsigned short* __restrict__ y, const float* __restrict__ b2,
    const int* __restrict__ t2e, const float* __restrict__ t2w,
    const int* __restrict__ t2p, float* __restrict__ out)
{
  const int t = blockIdx.x * 4 + (threadIdx.x >> 6);
  const int l = threadIdx.x & 63;
  const int e0 = t2e[t * 2], e1 = t2e[t * 2 + 1];
  const float w0 = t2w[t * 2], w1v = t2w[t * 2 + 1];
  const int p0 = t2p[t * 2], p1 = t2p[t * 2 + 1];
  const unsigned short* ya0 = y + (size_t)p0 * HDIM;
  const unsigned short* yb0 = y + (size_t)PMAX * HDIM + (size_t)p0 * HDIM;
  const unsigned short* ya1 = y + (size_t)p1 * HDIM;
  const unsigned short* yb1 = y + (size_t)PMAX * HDIM + (size_t)p1 * HDIM;
  const float* bb0 = b2 + e0 * HDIM;
  const float* bb1 = b2 + e1 * HDIM;
  float* o = out + (size_t)t * HDIM;
  #pragma unroll
  for (int j = 0; j < 4; ++j) {
    const int c = j * 256 + l * 4;
    const ushort4 a0 = *(const ushort4*)(ya0 + c);
    const ushort4 a1 = *(const ushort4*)(yb0 + c);
    const ushort4 b0v = *(const ushort4*)(ya1 + c);
    const ushort4 b1u = *(const ushort4*)(yb1 + c);
    const float4 c0 = *(const float4*)(bb0 + c);
    const float4 c1 = *(const float4*)(bb1 + c);
    float4 r;
    r.x = w0 * (b2f(a0.x) + b2f(a1.x) + c0.x) + w1v * (b2f(b0v.x) + b2f(b1u.x) + c1.x);
    r.y = w0 * (b2f(a0.y) + b2f(a1.y) + c0.y) + w1v * (b2f(b0v.y) + b2f(b1u.y) + c1.y);
    r.z = w0 * (b2f(a0.z) + b2f(a1.z) + c0.z) + w1v * (b2f(b0v.z) + b2f(b1u.z) + c1.z);
    r.w = w0 * (b2f(a0.w) + b2f(a1.w) + c0.w) + w1v * (b2f(b0v.w) + b2f(b1u.w) + c1.w);
    *(float4*)(o + c) = r;
  }
}

__global__ void sentinel_k(float* out) { out[0] = 1.0e6f; }

// ---------------- launcher ----------------
extern "C" void kernel_launch(void* const* d_in, const int* in_sizes, int n_in,
                              void* d_out, int out_size, void* d_ws, size_t ws_size,
                              hipStream_t stream)
{
  (void)in_sizes; (void)n_in; (void)out_size;
  const float* x  = (const float*)d_in[0];
  const float* wr = (const float*)d_in[1];
  const float* w1 = (const float*)d_in[2];
  const float* b1 = (const float*)d_in[3];
  const float* w2 = (const float*)d_in[4];
  const float* b2 = (const float*)d_in[5];
  float* out = (float*)d_out;
  char* ws = (char*)d_ws;

  if (ws_size < WS_NEED) { sentinel_k<<<1, 1, 0, stream>>>(out); return; }

  unsigned short* xb  = (unsigned short*)(ws);                 // 16.78 MB
  unsigned short* w1t = (unsigned short*)(ws + 16777216);      // 67.1 MB
  unsigned short* w2t = (unsigned short*)(ws + 83886080);      // 67.1 MB
  unsigned short* h   = (unsigned short*)(ws + 150994944);     // 151.0 MB
  int*   t2e  = (int*)(ws + 301989888);
  float* t2w  = (float*)(ws + 302055424);
  int*   ltok = (int*)(ws + 302120960);
  int*   t2p  = (int*)(ws + 302194688);
  int*   meta = (int*)(ws + 302260224);
  // y partials (bf16, 2 x 37.7MB) alias xb+w1t (dead after gemm1)
  unsigned short* y = (unsigned short*)(ws);

  hipFuncSetAttribute((const void*)gemm1_k, hipFuncAttributeMaxDynamicSharedMemorySize, 131072);
  hipFuncSetAttribute((const void*)gemm2_k, hipFuncAttributeMaxDynamicSharedMemorySize, 3 * SLOT2);

  prep_k<<<10240, 256, 0, stream>>>(x, wr, xb, t2e, t2w, w1, w1t, w2, w2t);
  scatter_k<<<NEXP, 256, 0, stream>>>(t2e, meta, ltok, t2p);

  gemm1_k<<<72 * 16, 512, 131072, stream>>>(xb, w1t, b1, meta, ltok, h);
  gemm2_k<<<144 * 8 * 2, 256, 3 * SLOT2, stream>>>(h, w2t, meta, y);
  combine_k<<<TTOK / 4, 256, 0, stream>>>(y, b2, t2e, t2w, t2p, out);
}

// Round 16
// 501.141 us; speedup vs baseline: 1.0695x; 1.0354x over previous
//
#include <hip/hip_runtime.h>
#include <cstdint>
#include <cstddef>

// ---------------- problem constants ----------------
#define TTOK 8192          // B*S tokens
#define HDIM 1024
#define IDIM 4096
#define NEXP 8
#define PMAX 18432         // 16384 + 8*256 (segment padding to 256)
#define WS_NEED 302260352ULL

// Both GEMMs: 256(N=wt/hcol) x 128(M=tok) block, BK=32, 256 thr
// (4 waves = 2 N-halves x 2 M-halves; wave tile 128x64), ring-3 of 24KB
// slots (A 16KB + B 8KB) = 72KB -> 2 blocks/CU. 0.375 ds_reads/MFMA
// (vs 0.5 at wave 64x64) -- attacks the LDS-read-BW cap.
#define SLOTG 24576

typedef __attribute__((ext_vector_type(8))) short bf16x8;
typedef __attribute__((ext_vector_type(4))) float f32x4;

#define AS3 __attribute__((address_space(3)))
#define AS1 __attribute__((address_space(1)))

__device__ __forceinline__ void gld16(const void* g, void* s) {
  // async global->LDS, 16B/lane; LDS dest is wave-uniform base (+lane*16 in HW)
  __builtin_amdgcn_global_load_lds((const AS1 void*)g, (AS3 void*)s, 16, 0, 0);
}

// Phase-opening barrier with selective fence: VMEM/DS may not cross (race
// guard, R8 lesson), ALU/VALU/SALU/MFMA may (overlap). R15-verified.
__device__ __forceinline__ void bar_fence() {
  __builtin_amdgcn_s_barrier();
  __builtin_amdgcn_sched_barrier(0xF);
}
__device__ __forceinline__ void bar_raw() {
  __builtin_amdgcn_s_barrier();
}

__device__ __forceinline__ unsigned short f2b(float f) {
  unsigned u = __builtin_bit_cast(unsigned, f);
  unsigned r = ((u >> 16) & 1u) + 0x7FFFu;   // RNE
  return (unsigned short)((u + r) >> 16);
}

__device__ __forceinline__ float b2f(unsigned short u) {
  return __builtin_bit_cast(float, ((unsigned)u) << 16);
}

// meta layout (ints): [16..23] offs, meta[24]=padded total

// ---------------- merged prep: router + packT(w1) + packT(w2) ----------------
__device__ __forceinline__ void router_body(
    int bid, int t, const float* __restrict__ x, const float* __restrict__ wr,
    unsigned short* __restrict__ xb, int* __restrict__ t2e,
    float* __restrict__ t2w)
{
  const int tok = bid * 4 + (t >> 6);
  const int l = t & 63;
  const float* xr = x + (size_t)tok * HDIM;
  float acc[8] = {0.f,0.f,0.f,0.f,0.f,0.f,0.f,0.f};
  #pragma unroll
  for (int j = 0; j < 4; ++j) {
    const int base = j * 256 + l * 4;
    const float4 xv = *(const float4*)(xr + base);
    const float xa[4] = {xv.x, xv.y, xv.z, xv.w};
    ushort4 ub;
    ub.x = f2b(xa[0]); ub.y = f2b(xa[1]); ub.z = f2b(xa[2]); ub.w = f2b(xa[3]);
    *(ushort4*)(xb + (size_t)tok * HDIM + base) = ub;
    #pragma unroll
    for (int ii = 0; ii < 4; ++ii) {
      const float4 w0 = *(const float4*)(wr + (size_t)(base + ii) * 8);
      const float4 w1 = *(const float4*)(wr + (size_t)(base + ii) * 8 + 4);
      acc[0] += xa[ii] * w0.x; acc[1] += xa[ii] * w0.y;
      acc[2] += xa[ii] * w0.z; acc[3] += xa[ii] * w0.w;
      acc[4] += xa[ii] * w1.x; acc[5] += xa[ii] * w1.y;
      acc[6] += xa[ii] * w1.z; acc[7] += xa[ii] * w1.w;
    }
  }
  #pragma unroll
  for (int e = 0; e < 8; ++e) {
    float v = acc[e];
    #pragma unroll
    for (int off = 32; off > 0; off >>= 1) v += __shfl_xor(v, off);
    acc[e] = v;
  }
  if (l == 0) {
    float l0 = -1e30f; int i0 = 0;
    #pragma unroll
    for (int e = 0; e < 8; ++e) if (acc[e] > l0) { l0 = acc[e]; i0 = e; }
    float l1 = -1e30f; int i1 = (i0 == 0) ? 1 : 0;
    #pragma unroll
    for (int e = 0; e < 8; ++e) if (e != i0 && acc[e] > l1) { l1 = acc[e]; i1 = e; }
    const float w0 = 1.f / (1.f + expf(l1 - l0));
    t2e[tok * 2] = i0; t2e[tok * 2 + 1] = i1;
    t2w[tok * 2] = w0; t2w[tok * 2 + 1] = 1.f - w0;
  }
}

__device__ __forceinline__ void packT_body(
    int bid, int t, uint32_t* __restrict__ plds,
    const float* __restrict__ src, unsigned short* __restrict__ dst,
    int K, int N)
{
  const int tiles_n = N >> 8, tiles_k = K >> 5;
  const int e = bid / (tiles_k * tiles_n);
  const int rem = bid % (tiles_k * tiles_n);
  const int kt = rem / tiles_n, it = rem % tiles_n;
  const float* S = src + (size_t)e * K * N + (size_t)kt * 32 * N + (size_t)it * 256;
  unsigned short* D = dst + (size_t)e * N * K + (size_t)it * 256 * K + (size_t)kt * 32;
  #pragma unroll
  for (int q = 0; q < 4; ++q) {
    const int task = q * 256 + t;
    const int i4 = task & 63, kp = task >> 6;
    const float* p0 = S + (size_t)(2 * kp) * N + i4 * 4;
    const float4 r0 = *(const float4*)p0;
    const float4 r1 = *(const float4*)(p0 + N);
    const float a0[4] = {r0.x, r0.y, r0.z, r0.w};
    const float a1[4] = {r1.x, r1.y, r1.z, r1.w};
    #pragma unroll
    for (int j = 0; j < 4; ++j)
      plds[(i4 * 4 + j) * 17 + kp] = (uint32_t)f2b(a0[j]) | ((uint32_t)f2b(a1[j]) << 16);
  }
  __syncthreads();
  #pragma unroll
  for (int r = 0; r < 4; ++r) {
    const int idx = r * 256 + t;
    const int il = idx >> 2, q4 = idx & 3;
    uint4 o;
    o.x = plds[il * 17 + q4 * 4 + 0];
    o.y = plds[il * 17 + q4 * 4 + 1];
    o.z = plds[il * 17 + q4 * 4 + 2];
    o.w = plds[il * 17 + q4 * 4 + 3];
    *(uint4*)(D + (size_t)il * K + q4 * 8) = o;
  }
}

__global__ __launch_bounds__(256, 2) void prep_k(
    const float* __restrict__ x, const float* __restrict__ wr,
    unsigned short* __restrict__ xb, int* __restrict__ t2e,
    float* __restrict__ t2w,
    const float* __restrict__ w1, unsigned short* __restrict__ w1t,
    const float* __restrict__ w2, unsigned short* __restrict__ w2t)
{
  __shared__ uint32_t plds[256 * 17];
  const int bid = blockIdx.x, t = threadIdx.x;
  if (bid < 2048) {
    router_body(bid, t, x, wr, xb, t2e, t2w);
  } else if (bid < 2048 + 4096) {
    packT_body(bid - 2048, t, plds, w1, w1t, HDIM, IDIM);
  } else {
    packT_body(bid - 6144, t, plds, w2, w2t, IDIM, HDIM);
  }
}

// ---- scatter (self-counting): per-expert deterministic prefix-scan scatter --
__global__ void scatter_k(const int* __restrict__ t2e, int* __restrict__ meta,
                          int* __restrict__ ltok, int* __restrict__ t2p)
{
  const int e = blockIdx.x;
  const int t = threadIdx.x, w = t >> 6, l = t & 63;
  __shared__ int part[4][8];
  __shared__ int soff, scnt;
  {
    int cnt[8] = {0,0,0,0,0,0,0,0};
    for (int c = 0; c < 32; ++c) {
      const int tok = (w * 32 + c) * 64 + l;
      const int e0 = t2e[2 * tok], e1 = t2e[2 * tok + 1];
      #pragma unroll
      for (int i = 0; i < 8; ++i)
        cnt[i] += __popcll(__ballot(e0 == i)) + __popcll(__ballot(e1 == i));
    }
    if (l == 0) {
      #pragma unroll
      for (int i = 0; i < 8; ++i) part[w][i] = cnt[i];
    }
  }
  __syncthreads();
  if (t == 0) {
    int off = 0, mycnt = 0, tot = 0;
    #pragma unroll
    for (int i = 0; i < 8; ++i) {
      const int s = part[0][i] + part[1][i] + part[2][i] + part[3][i];
      const int pad = (s + 255) & ~255;
      if (i == e) mycnt = s;
      if (i < e) off += pad;
      tot += pad;
    }
    soff = off; scnt = mycnt;
    meta[16 + e] = off;
    if (e == 0) meta[24] = tot;
  }
  __syncthreads();
  const int off = soff, cnt = scnt;

  __shared__ int wsum[4];
  __shared__ int base;
  if (t == 0) base = 0;
  __syncthreads();
  const unsigned long long lt = (1ULL << l) - 1ULL;
  for (int c = 0; c < TTOK / 256; ++c) {
    const int tok = c * 256 + t;
    const bool m0 = (t2e[2 * tok] == e);
    const bool m1 = (t2e[2 * tok + 1] == e);
    const unsigned long long b0 = __ballot(m0);
    const unsigned long long b1 = __ballot(m1);
    const int n0 = __popcll(b0), n1 = __popcll(b1);
    const int r0 = __popcll(b0 & lt);
    const int r1 = n0 + __popcll(b1 & lt);
    if (l == 0) wsum[w] = n0 + n1;
    __syncthreads();
    int wb = base;
    #pragma unroll
    for (int i = 0; i < 4; ++i) if (i < w) wb += wsum[i];
    const int tot = wsum[0] + wsum[1] + wsum[2] + wsum[3];
    __syncthreads();
    if (t == 0) base += tot;
    if (m0) { const int p = off + wb + r0; ltok[p] = tok; t2p[2 * tok] = p; }
    if (m1) { const int p = off + wb + r1; ltok[p] = tok; t2p[2 * tok + 1] = p; }
    __syncthreads();
  }
  const int padded = (cnt + 255) & ~255;
  for (int i = cnt + t; i < padded; i += 256) ltok[off + i] = -1;
}

// LDS swizzle (bijective, verified rounds 2-15, bank-conflict==0): granule G
// of an operand region maps to (row,g): line=G>>3, q=(G&7)^(line&7),
// row=2*line+(q>>2), g=q&3. Stage keeps LDS dest linear (gld16) with
// inverse-swizzled global source; reads use line=row>>1,
// p=((row&1)*4+g)^(line&7), byte = line*128 + p*16.
// Race-safe schedule per K-tile (R13/R15 proven, L=6 loads/stage):
//   vmcnt(6 | 0-at-tail); bar_fence; 12 ds_reads(slot kt); STAGE(kt+2);
//   setprio(1); 32 MFMA; setprio(0); bar_raw.
// Slot layout: A (256 N-rows, 16KB) @ +0; B (128 M-rows, 8KB) @ +16384.
// Waves: wn=w&1 (N-half of 128), wm=w>>1 (M-half of 64); wave tile 128x64.

// ---------------- grouped GEMM1: h = silu(W1T-tile x Xg-tile + b1) -----------
__global__ __launch_bounds__(256, 2) void gemm1_k(
    const unsigned short* __restrict__ xb, const unsigned short* __restrict__ w1t,
    const float* __restrict__ b1, const int* __restrict__ meta,
    const int* __restrict__ ltok, unsigned short* __restrict__ h)
{
  const int wg = blockIdx.x;                       // 2304 = 144*16, %8==0
  const int id = (wg & 7) * (2304 / 8) + (wg >> 3);
  const int mt = id >> 4, nt = id & 15;
  if (mt * 128 >= meta[24]) return;
  int e = 0;
  #pragma unroll
  for (int i = 1; i < 8; ++i) if (meta[16 + i] <= mt * 128) e = i;

  extern __shared__ char lds[];                    // 3 slots x 24KB
  const int t = threadIdx.x;
  const int w = t >> 6, l = t & 63;
  const int wn = w & 1, wm = w >> 1;
  const int lr = l & 15, lg = l >> 4;

  // A sources (4 granules/thread): G = c*256 + t, W1T rows nt*256+row
  const unsigned short* asrc[4];
  #pragma unroll
  for (int c = 0; c < 4; ++c) {
    const int G = c * 256 + t;
    const int line = G >> 3, q = (G & 7) ^ (line & 7);
    const int row = 2 * line + (q >> 2), g = q & 3;
    asrc[c] = w1t + ((size_t)e * IDIM + nt * 256 + row) * HDIM + g * 8;
  }
  // B sources (2 granules/thread): gathered token rows mt*128+row
  const unsigned short* bsrc[2];
  #pragma unroll
  for (int c = 0; c < 2; ++c) {
    const int G = c * 256 + t;
    const int line = G >> 3, q = (G & 7) ^ (line & 7);
    const int row = 2 * line + (q >> 2), g = q & 3;
    int tok = ltok[mt * 128 + row]; if (tok < 0) tok = 0;
    bsrc[c] = xb + (size_t)tok * HDIM + g * 8;
  }

  f32x4 acc[8][4] = {};

  auto STAGE = [&](int kt) {
    char* sb = lds + (kt % 3) * SLOTG;
    const int ks = kt * 32;
    #pragma unroll
    for (int c = 0; c < 4; ++c) gld16(asrc[c] + ks, sb + c * 4096 + w * 1024);
    #pragma unroll
    for (int c = 0; c < 2; ++c) gld16(bsrc[c] + ks, sb + 16384 + c * 4096 + w * 1024);
  };

  STAGE(0); STAGE(1);
  const int NT = HDIM / 32;                        // 32
  for (int kt = 0; kt < NT; ++kt) {
    if (kt + 1 < NT) {
      asm volatile("s_waitcnt vmcnt(6)" ::: "memory");
    } else {
      asm volatile("s_waitcnt vmcnt(0)" ::: "memory");
    }
    bar_fence();
    const char* sl = lds + (kt % 3) * SLOTG;
    bf16x8 af[8], bf[4];
    #pragma unroll
    for (int f = 0; f < 8; ++f) {
      const int rowA = wn * 128 + f * 16 + lr;
      const int lineA = rowA >> 1;
      const int pA = (((rowA & 1) << 2) + lg) ^ (lineA & 7);
      af[f] = *(const bf16x8*)(sl + lineA * 128 + pA * 16);
    }
    #pragma unroll
    for (int f = 0; f < 4; ++f) {
      const int rowB = wm * 64 + f * 16 + lr;
      const int lineB = rowB >> 1;
      const int pB = (((rowB & 1) << 2) + lg) ^ (lineB & 7);
      bf[f] = *(const bf16x8*)(sl + 16384 + lineB * 128 + pB * 16);
    }
    if (kt + 2 < NT) STAGE(kt + 2);
    __builtin_amdgcn_s_setprio(1);
    #pragma unroll
    for (int fm = 0; fm < 8; ++fm)
      #pragma unroll
      for (int fn = 0; fn < 4; ++fn)
        acc[fm][fn] = __builtin_amdgcn_mfma_f32_16x16x32_bf16(af[fm], bf[fn], acc[fm][fn], 0, 0, 0);
    __builtin_amdgcn_s_setprio(0);
    bar_raw();
  }

  // epilogue: +b1, silu, packed ushort4 stores (D reg-dim = i, col = token)
  const int lg4 = lg * 4;
  #pragma unroll
  for (int fm = 0; fm < 8; ++fm) {
    const int ib = nt * 256 + wn * 128 + fm * 16 + lg4;
    const float4 b1v = *(const float4*)(b1 + e * IDIM + ib);
    #pragma unroll
    for (int fn = 0; fn < 4; ++fn) {
      const int trow = mt * 128 + wm * 64 + fn * 16 + lr;
      const float v0 = acc[fm][fn][0] + b1v.x;
      const float v1 = acc[fm][fn][1] + b1v.y;
      const float v2 = acc[fm][fn][2] + b1v.z;
      const float v3 = acc[fm][fn][3] + b1v.w;
      ushort4 st;
      st.x = f2b(v0 / (1.f + __expf(-v0)));
      st.y = f2b(v1 / (1.f + __expf(-v1)));
      st.z = f2b(v2 / (1.f + __expf(-v2)));
      st.w = f2b(v3 / (1.f + __expf(-v3)));
      *(ushort4*)(h + (size_t)trow * IDIM + ib) = st;
    }
  }
}

// ---------------- grouped GEMM2: y_kh = h @ W2T^T over K-half ---------------
__global__ __launch_bounds__(256, 2) void gemm2_k(
    const unsigned short* __restrict__ h, const unsigned short* __restrict__ w2t,
    const int* __restrict__ meta, unsigned short* __restrict__ y)
{
  const int wg = blockIdx.x;                       // 1152 = 144*4*2, %8==0
  const int id = (wg & 7) * (1152 / 8) + (wg >> 3);
  const int nt = id & 3, kh = (id >> 2) & 1, mt = id >> 3;
  if (mt * 128 >= meta[24]) return;
  int e = 0;
  #pragma unroll
  for (int i = 1; i < 8; ++i) if (meta[16 + i] <= mt * 128) e = i;

  extern __shared__ char lds[];
  const int t = threadIdx.x;
  const int w = t >> 6, l = t & 63;
  const int wn = w & 1, wm = w >> 1;
  const int lr = l & 15, lg = l >> 4;
  const int kbase = kh * (IDIM / 2);

  // A = W2T rows (hcol-dim, nt tile of 256); B = h token rows (mt tile of 128)
  const unsigned short* asrc[4];
  #pragma unroll
  for (int c = 0; c < 4; ++c) {
    const int G = c * 256 + t;
    const int line = G >> 3, q = (G & 7) ^ (line & 7);
    const int row = 2 * line + (q >> 2), g = q & 3;
    asrc[c] = w2t + ((size_t)e * HDIM + nt * 256 + row) * IDIM + kbase + g * 8;
  }
  const unsigned short* bsrc[2];
  #pragma unroll
  for (int c = 0; c < 2; ++c) {
    const int G = c * 256 + t;
    const int line = G >> 3, q = (G & 7) ^ (line & 7);
    const int row = 2 * line + (q >> 2), g = q & 3;
    bsrc[c] = h + (size_t)(mt * 128 + row) * IDIM + kbase + g * 8;
  }

  f32x4 acc[8][4] = {};

  auto STAGE = [&](int kt) {
    char* sb = lds + (kt % 3) * SLOTG;
    const int ks = kt * 32;
    #pragma unroll
    for (int c = 0; c < 4; ++c) gld16(asrc[c] + ks, sb + c * 4096 + w * 1024);
    #pragma unroll
    for (int c = 0; c < 2; ++c) gld16(bsrc[c] + ks, sb + 16384 + c * 4096 + w * 1024);
  };

  STAGE(0); STAGE(1);
  const int NT = IDIM / 2 / 32;                    // 64
  for (int kt = 0; kt < NT; ++kt) {
    if (kt + 1 < NT) {
      asm volatile("s_waitcnt vmcnt(6)" ::: "memory");
    } else {
      asm volatile("s_waitcnt vmcnt(0)" ::: "memory");
    }
    bar_fence();
    const char* sl = lds + (kt % 3) * SLOTG;
    bf16x8 af[8], bf[4];
    #pragma unroll
    for (int f = 0; f < 8; ++f) {
      const int rowA = wn * 128 + f * 16 + lr;
      const int lineA = rowA >> 1;
      const int pA = (((rowA & 1) << 2) + lg) ^ (lineA & 7);
      af[f] = *(const bf16x8*)(sl + lineA * 128 + pA * 16);
    }
    #pragma unroll
    for (int f = 0; f < 4; ++f) {
      const int rowB = wm * 64 + f * 16 + lr;
      const int lineB = rowB >> 1;
      const int pB = (((rowB & 1) << 2) + lg) ^ (lineB & 7);
      bf[f] = *(const bf16x8*)(sl + 16384 + lineB * 128 + pB * 16);
    }
    if (kt + 2 < NT) STAGE(kt + 2);
    __builtin_amdgcn_s_setprio(1);
    #pragma unroll
    for (int fm = 0; fm < 8; ++fm)
      #pragma unroll
      for (int fn = 0; fn < 4; ++fn)
        acc[fm][fn] = __builtin_amdgcn_mfma_f32_16x16x32_bf16(af[fm], bf[fn], acc[fm][fn], 0, 0, 0);
    __builtin_amdgcn_s_setprio(0);
    bar_raw();
  }

  // epilogue: bf16 ushort4 stores into the kh partial buffer
  unsigned short* yo = y + (size_t)kh * PMAX * HDIM;
  const int lg4 = lg * 4;
  #pragma unroll
  for (int fm = 0; fm < 8; ++fm) {
    const int colb = nt * 256 + wn * 128 + fm * 16 + lg4;
    #pragma unroll
    for (int fn = 0; fn < 4; ++fn) {
      const int row = mt * 128 + wm * 64 + fn * 16 + lr;
      ushort4 st;
      st.x = f2b(acc[fm][fn][0]); st.y = f2b(acc[fm][fn][1]);
      st.z = f2b(acc[fm][fn][2]); st.w = f2b(acc[fm][fn][3]);
      *(ushort4*)(yo + (size_t)row * HDIM + colb) = st;
    }
  }
}

// ---- combine: out[t] = w0*(y0[p0]+y1[p0]+b2[e0]) + w1*(y0[p1]+y1[p1]+b2[e1])
__global__ __launch_bounds__(256, 4) void combine_k(
    const unsigned short* __restrict__ y, const float* __restrict__ b2,
    const int* __restrict__ t2e, const float* __restrict__ t2w,
    const int* __restrict__ t2p, float* __restrict__ out)
{
  const int t = blockIdx.x * 4 + (threadIdx.x >> 6);
  const int l = threadIdx.x & 63;
  const int e0 = t2e[t * 2], e1 = t2e[t * 2 + 1];
  const float w0 = t2w[t * 2], w1v = t2w[t * 2 + 1];
  const int p0 = t2p[t * 2], p1 = t2p[t * 2 + 1];
  const unsigned short* ya0 = y + (size_t)p0 * HDIM;
  const unsigned short* yb0 = y + (size_t)PMAX * HDIM + (size_t)p0 * HDIM;
  const unsigned short* ya1 = y + (size_t)p1 * HDIM;
  const unsigned short* yb1 = y + (size_t)PMAX * HDIM + (size_t)p1 * HDIM;
  const float* bb0 = b2 + e0 * HDIM;
  const float* bb1 = b2 + e1 * HDIM;
  float* o = out + (size_t)t * HDIM;
  #pragma unroll
  for (int j = 0; j < 4; ++j) {
    const int c = j * 256 + l * 4;
    const ushort4 a0 = *(const ushort4*)(ya0 + c);
    const ushort4 a1 = *(const ushort4*)(yb0 + c);
    const ushort4 b0v = *(const ushort4*)(ya1 + c);
    const ushort4 b1u = *(const ushort4*)(yb1 + c);
    const float4 c0 = *(const float4*)(bb0 + c);
    const float4 c1 = *(const float4*)(bb1 + c);
    float4 r;
    r.x = w0 * (b2f(a0.x) + b2f(a1.x) + c0.x) + w1v * (b2f(b0v.x) + b2f(b1u.x) + c1.x);
    r.y = w0 * (b2f(a0.y) + b2f(a1.y) + c0.y) + w1v * (b2f(b0v.y) + b2f(b1u.y) + c1.y);
    r.z = w0 * (b2f(a0.z) + b2f(a1.z) + c0.z) + w1v * (b2f(b0v.z) + b2f(b1u.z) + c1.z);
    r.w = w0 * (b2f(a0.w) + b2f(a1.w) + c0.w) + w1v * (b2f(b0v.w) + b2f(b1u.w) + c1.w);
    *(float4*)(o + c) = r;
  }
}

__global__ void sentinel_k(float* out) { out[0] = 1.0e6f; }

// ---------------- launcher ----------------
extern "C" void kernel_launch(void* const* d_in, const int* in_sizes, int n_in,
                              void* d_out, int out_size, void* d_ws, size_t ws_size,
                              hipStream_t stream)
{
  (void)in_sizes; (void)n_in; (void)out_size;
  const float* x  = (const float*)d_in[0];
  const float* wr = (const float*)d_in[1];
  const float* w1 = (const float*)d_in[2];
  const float* b1 = (const float*)d_in[3];
  const float* w2 = (const float*)d_in[4];
  const float* b2 = (const float*)d_in[5];
  float* out = (float*)d_out;
  char* ws = (char*)d_ws;

  if (ws_size < WS_NEED) { sentinel_k<<<1, 1, 0, stream>>>(out); return; }

  unsigned short* xb  = (unsigned short*)(ws);                 // 16.78 MB
  unsigned short* w1t = (unsigned short*)(ws + 16777216);      // 67.1 MB
  unsigned short* w2t = (unsigned short*)(ws + 83886080);      // 67.1 MB
  unsigned short* h   = (unsigned short*)(ws + 150994944);     // 151.0 MB
  int*   t2e  = (int*)(ws + 301989888);
  float* t2w  = (float*)(ws + 302055424);
  int*   ltok = (int*)(ws + 302120960);
  int*   t2p  = (int*)(ws + 302194688);
  int*   meta = (int*)(ws + 302260224);
  // y partials (bf16, 2 x 37.7MB) alias xb+w1t (dead after gemm1)
  unsigned short* y = (unsigned short*)(ws);

  hipFuncSetAttribute((const void*)gemm1_k, hipFuncAttributeMaxDynamicSharedMemorySize, 3 * SLOTG);
  hipFuncSetAttribute((const void*)gemm2_k, hipFuncAttributeMaxDynamicSharedMemorySize, 3 * SLOTG);

  prep_k<<<10240, 256, 0, stream>>>(x, wr, xb, t2e, t2w, w1, w1t, w2, w2t);
  scatter_k<<<NEXP, 256, 0, stream>>>(t2e, meta, ltok, t2p);

  gemm1_k<<<144 * 16, 256, 3 * SLOTG, stream>>>(xb, w1t, b1, meta, ltok, h);
  gemm2_k<<<144 * 4 * 2, 256, 3 * SLOTG, stream>>>(h, w2t, meta, y);
  combine_k<<<TTOK / 4, 256, 0, stream>>>(y, b2, t2e, t2w, t2p, out);
}